// Round 2
// baseline (6320.973 us; speedup 1.0000x reference)
//
#include <hip/hip_runtime.h>

#define TOL 1e-6f
#define NITER 101
#define H 256
#define W 256
#define HW 65536
#define NHW 262144
#define NBLK 256
#define TPB 256

// ws float offsets
#define WS_D    0              // NHW floats: d = sum_c mask*p  [B,H,W]
#define WS_CRIT (NHW)          // 102 floats: crit_0..crit_101
#define WS_DEN  (NHW + 102)    // 101 floats: denom_0..denom_100
#define WS_BARF (NHW + 256)    // barrier state: 512 uints

// ---------------------------------------------------------------------------
// two-level grid barrier: 16 groups x 16 blocks -> master -> generation flip
// bar[g*16] group counters (64B apart), bar[256] master, bar[272] generation
// ---------------------------------------------------------------------------
__device__ __forceinline__ void grid_barrier(unsigned* bar) {
    __syncthreads();
    if (threadIdx.x == 0) {
        unsigned g = __hip_atomic_load(&bar[272], __ATOMIC_RELAXED, __HIP_MEMORY_SCOPE_AGENT);
        unsigned grp = blockIdx.x >> 4;
        unsigned r = __hip_atomic_fetch_add(&bar[grp * 16], 1u, __ATOMIC_ACQ_REL, __HIP_MEMORY_SCOPE_AGENT);
        if (r == 15u) {
            unsigned r2 = __hip_atomic_fetch_add(&bar[256], 1u, __ATOMIC_ACQ_REL, __HIP_MEMORY_SCOPE_AGENT);
            if (r2 == 15u) {
                #pragma unroll
                for (int i = 0; i < 16; ++i)
                    __hip_atomic_store(&bar[i * 16], 0u, __ATOMIC_RELAXED, __HIP_MEMORY_SCOPE_AGENT);
                __hip_atomic_store(&bar[256], 0u, __ATOMIC_RELAXED, __HIP_MEMORY_SCOPE_AGENT);
                __hip_atomic_store(&bar[272], g + 1u, __ATOMIC_RELEASE, __HIP_MEMORY_SCOPE_AGENT);
            }
        }
        while (__hip_atomic_load(&bar[272], __ATOMIC_ACQUIRE, __HIP_MEMORY_SCOPE_AGENT) == g)
            __builtin_amdgcn_s_sleep(1);
    }
    __syncthreads();
}

__device__ __forceinline__ void block_reduce_atomic(float v, float* dst) {
    #pragma unroll
    for (int off = 32; off; off >>= 1)
        v += __shfl_down(v, off, 64);
    __shared__ float red_[4];
    const int lane = threadIdx.x & 63, wid = threadIdx.x >> 6;
    if (lane == 0) red_[wid] = v;
    __syncthreads();
    if (threadIdx.x == 0)
        atomicAdd(dst, red_[0] + red_[1] + red_[2] + red_[3]);
    __syncthreads();
}

// conv P: dext[36x36] -> tsh[3][34x34], cropped to image (zeros outside)
__device__ __forceinline__ void conv_p(const float* dext, float* tsh,
                                       const float* ksh, int tid, int h0, int w0) {
    for (int e = tid; e < 1156; e += TPB) {
        const int th = e / 34, tw = e - th * 34;
        const int gh = h0 + th - 1, gw = w0 + tw - 1;
        float t0 = 0.f, t1 = 0.f, t2 = 0.f;
        if ((unsigned)gh < (unsigned)H && (unsigned)gw < (unsigned)W) {
            #pragma unroll
            for (int i = 0; i < 3; ++i)
                #pragma unroll
                for (int j = 0; j < 3; ++j) {
                    const float v = dext[(th + i) * 36 + tw + j];
                    t0 += v * ksh[i * 3 + j];
                    t1 += v * ksh[9 + i * 3 + j];
                    t2 += v * ksh[18 + i * 3 + j];
                }
        }
        tsh[e] = t0; tsh[1156 + e] = t1; tsh[2312 + e] = t2;
    }
}

// conv PT at core position (h,w) from tsh
__device__ __forceinline__ float conv_pt(const float* tsh, const float* ksh, int h, int w) {
    float q = 0.f;
    #pragma unroll
    for (int o = 0; o < 3; ++o)
        #pragma unroll
        for (int i = 0; i < 3; ++i)
            #pragma unroll
            for (int j = 0; j < 3; ++j)
                q += tsh[o * 1156 + (h + i) * 34 + (w + j)] * ksh[o * 9 + (2 - i) * 3 + (2 - j)];
    return q;
}

// fill dext: core from registers, 272-elem halo ring from global d
__device__ __forceinline__ void fill_dext(float* dext, const float* d, const float dv[4],
                                          int tid, int bi, int h0, int w0) {
    #pragma unroll
    for (int k = 0; k < 4; ++k) {
        const int e = tid + (k << 8);
        dext[((e >> 5) + 2) * 36 + (e & 31) + 2] = dv[k];
    }
    for (int t = tid; t < 272; t += TPB) {
        int eh, ew;
        if (t < 72)       { eh = t / 36;                  ew = t - eh * 36; }
        else if (t < 144) { const int u = t - 72;  eh = 34 + u / 36; ew = u - (u / 36) * 36; }
        else              { const int u = t - 144; eh = 2 + (u >> 2);
                            const int c2 = u & 3;  ew = (c2 < 2) ? c2 : c2 + 32; }
        const int gh = h0 + eh - 2, gw = w0 + ew - 2;
        float v = 0.f;
        if ((unsigned)gh < (unsigned)H && (unsigned)gw < (unsigned)W)
            v = d[bi * HW + gh * W + gw];
        dext[eh * 36 + ew] = v;
    }
}

extern "C" __global__ void __launch_bounds__(TPB)
cg_persistent(const float* __restrict__ mask, const float* __restrict__ y,
              const float* __restrict__ z, const float* __restrict__ bet,
              const float* __restrict__ rho_p, const float* __restrict__ kern,
              float* __restrict__ x_out, float* __restrict__ ws)
{
    __shared__ float ksh[27];
    __shared__ float dext[36 * 36];
    __shared__ float tsh[3 * 1156];

    float* d = ws + WS_D;
    float* sc_crit = ws + WS_CRIT;
    float* sc_den  = ws + WS_DEN;
    unsigned* bar  = (unsigned*)(ws + WS_BARF);

    const int tid = threadIdx.x;
    const int T = blockIdx.x;          // 0..255: bi(2) | tile_row(3) | tile_col(3)
    const int bi = T >> 6;
    const int h0 = ((T >> 3) & 7) << 5;
    const int w0 = (T & 7) << 5;

    if (tid < 27) ksh[tid] = kern[tid];
    const float rho = rho_p[0];

    // register-resident state: thread owns core elems e = tid + k*256, k=0..3
    float m_[3][4], p_[3][4], r_[3][4], x_[3][4], Ap_[3][4], dv[4];
    int roff[4];
    #pragma unroll
    for (int k = 0; k < 4; ++k) {
        const int e = tid + (k << 8);
        roff[k] = (h0 + (e >> 5)) * W + w0 + (e & 31);
    }
    #pragma unroll
    for (int c = 0; c < 3; ++c)
        #pragma unroll
        for (int k = 0; k < 4; ++k)
            m_[c][k] = mask[(bi * 3 + c) * HW + roff[k]];

    // ---- init part 1: q0 = PT(P(y));  b = m*q0 + rho*(z-beta); x=b; d0 = sum m*b
    for (int e = tid; e < 1296; e += TPB) {
        const int eh = e / 36, ew = e - eh * 36;
        const int gh = h0 + eh - 2, gw = w0 + ew - 2;
        float v = 0.f;
        if ((unsigned)gh < (unsigned)H && (unsigned)gw < (unsigned)W)
            v = y[bi * HW + gh * W + gw];
        dext[e] = v;
    }
    __syncthreads();
    conv_p(dext, tsh, ksh, tid, h0, w0);
    __syncthreads();
    #pragma unroll
    for (int k = 0; k < 4; ++k) {
        const int e = tid + (k << 8);
        const float q = conv_pt(tsh, ksh, e >> 5, e & 31);
        float s = 0.f;
        #pragma unroll
        for (int c = 0; c < 3; ++c) {
            const int gi = (bi * 3 + c) * HW + roff[k];
            const float b = m_[c][k] * q + rho * (z[gi] - bet[gi]);
            x_[c][k] = b;
            s += m_[c][k] * b;
        }
        dv[k] = s;
        d[bi * HW + roff[k]] = s;
    }
    grid_barrier(bar);

    // ---- init part 2: Ap0 = A(x0); r = p = b - Ap0; crit0
    __syncthreads();
    fill_dext(dext, d, dv, tid, bi, h0, w0);
    __syncthreads();
    conv_p(dext, tsh, ksh, tid, h0, w0);
    __syncthreads();
    float csum0 = 0.f;
    #pragma unroll
    for (int k = 0; k < 4; ++k) {
        const int e = tid + (k << 8);
        const float q = conv_pt(tsh, ksh, e >> 5, e & 31);
        #pragma unroll
        for (int c = 0; c < 3; ++c) {
            const float b = x_[c][k];
            const float rv = b - (rho * b + m_[c][k] * q);
            r_[c][k] = rv;
            p_[c][k] = rv;
            csum0 += rv * rv;
        }
    }
    block_reduce_atomic(csum0, &sc_crit[0]);
    grid_barrier(bar);

    // ---- CG loop
    for (int j = 0; j < NITER; ++j) {
        const float critj = __hip_atomic_load(&sc_crit[j], __ATOMIC_RELAXED, __HIP_MEMORY_SCOPE_AGENT);
        const bool active = critj >= TOL;

        // phase A: d = sum_c m*p  (own core)
        #pragma unroll
        for (int k = 0; k < 4; ++k) {
            float s = 0.f;
            #pragma unroll
            for (int c = 0; c < 3; ++c) s += m_[c][k] * p_[c][k];
            dv[k] = s;
            d[bi * HW + roff[k]] = s;
        }
        grid_barrier(bar);

        // phase C: conv PT(P(d)); Ap; denom
        fill_dext(dext, d, dv, tid, bi, h0, w0);
        __syncthreads();
        conv_p(dext, tsh, ksh, tid, h0, w0);
        __syncthreads();
        float dsum = 0.f;
        #pragma unroll
        for (int k = 0; k < 4; ++k) {
            const int e = tid + (k << 8);
            const float q = conv_pt(tsh, ksh, e >> 5, e & 31);
            #pragma unroll
            for (int c = 0; c < 3; ++c) {
                const float ap = rho * p_[c][k] + m_[c][k] * q;
                Ap_[c][k] = ap;
                dsum += p_[c][k] * ap;
            }
        }
        block_reduce_atomic(dsum, &sc_den[j]);
        grid_barrier(bar);

        // phase E: alpha; x,r update; crit_{j+1}
        const float denom = __hip_atomic_load(&sc_den[j], __ATOMIC_RELAXED, __HIP_MEMORY_SCOPE_AGENT);
        const float alpha = critj / (active ? denom : 1.0f);
        float csum = 0.f;
        #pragma unroll
        for (int c = 0; c < 3; ++c)
            #pragma unroll
            for (int k = 0; k < 4; ++k) {
                if (active) {
                    x_[c][k] += alpha * p_[c][k];
                    r_[c][k] -= alpha * Ap_[c][k];
                }
                csum += r_[c][k] * r_[c][k];
            }
        block_reduce_atomic(csum, &sc_crit[j + 1]);
        grid_barrier(bar);

        // phase F: beta; p update
        const float critn = __hip_atomic_load(&sc_crit[j + 1], __ATOMIC_RELAXED, __HIP_MEMORY_SCOPE_AGENT);
        const float beta = critn / (active ? critj : 1.0f);
        if (active) {
            #pragma unroll
            for (int c = 0; c < 3; ++c)
                #pragma unroll
                for (int k = 0; k < 4; ++k)
                    p_[c][k] = r_[c][k] + beta * p_[c][k];
        }
    }

    // final store
    #pragma unroll
    for (int c = 0; c < 3; ++c)
        #pragma unroll
        for (int k = 0; k < 4; ++k)
            x_out[(bi * 3 + c) * HW + roff[k]] = x_[c][k];
}

extern "C" void kernel_launch(void* const* d_in, const int* in_sizes, int n_in,
                              void* d_out, int out_size, void* d_ws, size_t ws_size,
                              hipStream_t stream)
{
    const float* mask = (const float*)d_in[0];
    const float* y    = (const float*)d_in[1];
    const float* z    = (const float*)d_in[2];
    const float* bet  = (const float*)d_in[3];
    const float* rho  = (const float*)d_in[4];
    const float* kern = (const float*)d_in[5];
    float* x  = (float*)d_out;
    float* ws = (float*)d_ws;

    // zero scalar slots + barrier state (ws is re-poisoned before every call)
    hipMemsetAsync(ws + NHW, 0, 1024 * sizeof(float), stream);

    void* args[] = { (void*)&mask, (void*)&y, (void*)&z, (void*)&bet,
                     (void*)&rho, (void*)&kern, (void*)&x, (void*)&ws };
    hipLaunchCooperativeKernel((void*)cg_persistent, dim3(NBLK), dim3(TPB),
                               args, 0, stream);
}

// Round 3
// 1607.522 us; speedup vs baseline: 3.9321x; 3.9321x over previous
//
#include <hip/hip_runtime.h>

#define TOL 1e-6f
#define NITER 101
#define H 256
#define W 256
#define HW 65536
#define NCHW 786432
#define NBLK 256
#define TPB 256

// ws float offsets: rbuf[NCHW] | sc[256] | bar[512 uints]
#define WS_SC  NCHW
#define WS_BAR (NCHW + 256)

// bar uint offsets (16-uint = 64B stride to avoid false sharing)
#define B_XCNT 0     // per-XCD population (8 slots)
#define B_LCNT 128   // per-XCD arrival counters (monotonic)
#define B_LGEN 256   // per-XCD generation (release lines)
#define B_GCNT 384   // master arrival counter
#define B_GGEN 400   // master generation
#define B_ICNT 416   // init population sync

#define LD_AG(p)    __hip_atomic_load((p), __ATOMIC_RELAXED, __HIP_MEMORY_SCOPE_AGENT)
#define ST_AG(p,v)  __hip_atomic_store((p), (v), __ATOMIC_RELAXED, __HIP_MEMORY_SCOPE_AGENT)

__device__ __forceinline__ unsigned opaque_zero() {
    unsigned z; asm volatile("s_mov_b32 %0, 0" : "=s"(z)); return z;
}

// RMW poll primitive: atomic RMWs always execute at >= L2, so they can never
// read a stale L1 line (a relaxed atomic *load* at workgroup scope could).
__device__ __forceinline__ unsigned rmw_add(unsigned* p, unsigned v, bool agent) {
    return agent ? __hip_atomic_fetch_add(p, v, __ATOMIC_RELAXED, __HIP_MEMORY_SCOPE_AGENT)
                 : __hip_atomic_fetch_add(p, v, __ATOMIC_RELAXED, __HIP_MEMORY_SCOPE_WORKGROUP);
}

// hierarchical grid barrier: per-XCD L2 arrival -> 8 leaders at LLC -> release
// fan-out via per-XCD L2 lines. Monotonic generation counters, no resets.
__device__ __forceinline__ void xbar(unsigned* bar, unsigned rnd, unsigned my_xcc,
                                     unsigned xn, unsigned ng, bool agent_loc) {
    asm volatile("s_waitcnt vmcnt(0)" ::: "memory");
    __syncthreads();
    if (threadIdx.x == 0) {
        const unsigned z = opaque_zero();
        unsigned a = rmw_add(bar + B_LCNT + 16 * my_xcc, 1u, agent_loc);
        if (a == rnd * xn - 1u) {                       // XCD leader this round
            unsigned g = __hip_atomic_fetch_add(bar + B_GCNT, 1u,
                             __ATOMIC_RELAXED, __HIP_MEMORY_SCOPE_AGENT);
            if (g == rnd * ng - 1u) {                   // global master
                __hip_atomic_store(bar + B_GGEN, rnd,
                                   __ATOMIC_RELAXED, __HIP_MEMORY_SCOPE_AGENT);
            } else {
                while (__hip_atomic_fetch_add(bar + B_GGEN, z, __ATOMIC_RELAXED,
                                              __HIP_MEMORY_SCOPE_AGENT) < rnd)
                    __builtin_amdgcn_s_sleep(4);
            }
            if (agent_loc)
                __hip_atomic_store(bar + B_LGEN + 16 * my_xcc, rnd,
                                   __ATOMIC_RELAXED, __HIP_MEMORY_SCOPE_AGENT);
            else
                __hip_atomic_store(bar + B_LGEN + 16 * my_xcc, rnd,
                                   __ATOMIC_RELAXED, __HIP_MEMORY_SCOPE_WORKGROUP);
        } else {
            while (rmw_add(bar + B_LGEN + 16 * my_xcc, z, agent_loc) < rnd)
                __builtin_amdgcn_s_sleep(2);
        }
    }
    __syncthreads();
}

__device__ __forceinline__ void block_reduce_atomic(float v, float* dst) {
    #pragma unroll
    for (int off = 32; off; off >>= 1)
        v += __shfl_down(v, off, 64);
    __shared__ float red_[4];
    const int lane = threadIdx.x & 63, wid = threadIdx.x >> 6;
    if (lane == 0) red_[wid] = v;
    __syncthreads();
    if (threadIdx.x == 0)
        atomicAdd(dst, red_[0] + red_[1] + red_[2] + red_[3]);
    __syncthreads();
}

// halo ring (36x36 minus 32x32 core): 272 positions
__device__ __forceinline__ void ring_pos(int t, int& eh, int& ew) {
    if (t < 72)       { eh = t / 36;                 ew = t - (t / 36) * 36; }
    else if (t < 144) { const int u = t - 72;  eh = 34 + u / 36; ew = u - (u / 36) * 36; }
    else              { const int u = t - 144; eh = 2 + (u >> 2);
                        const int c2 = u & 3;  ew = (c2 < 2) ? c2 : c2 + 32; }
}

// conv P: dext[36x36] -> tsh[3][34x34], cropped to image (zeros outside)
__device__ __forceinline__ void conv_p(const float* dext, float* tsh,
                                       const float* ksh, int tid, int h0, int w0) {
    for (int e = tid; e < 1156; e += TPB) {
        const int th = e / 34, tw = e - th * 34;
        const int gh = h0 + th - 1, gw = w0 + tw - 1;
        float t0 = 0.f, t1 = 0.f, t2 = 0.f;
        if ((unsigned)gh < (unsigned)H && (unsigned)gw < (unsigned)W) {
            #pragma unroll
            for (int i = 0; i < 3; ++i)
                #pragma unroll
                for (int j = 0; j < 3; ++j) {
                    const float v = dext[(th + i) * 36 + tw + j];
                    t0 += v * ksh[i * 3 + j];
                    t1 += v * ksh[9 + i * 3 + j];
                    t2 += v * ksh[18 + i * 3 + j];
                }
        }
        tsh[e] = t0; tsh[1156 + e] = t1; tsh[2312 + e] = t2;
    }
}

__device__ __forceinline__ float conv_pt(const float* tsh, const float* ksh, int h, int w) {
    float q = 0.f;
    #pragma unroll
    for (int o = 0; o < 3; ++o)
        #pragma unroll
        for (int i = 0; i < 3; ++i)
            #pragma unroll
            for (int j = 0; j < 3; ++j)
                q += tsh[o * 1156 + (h + i) * 34 + (w + j)] * ksh[o * 9 + (2 - i) * 3 + (2 - j)];
    return q;
}

extern "C" __global__ void __launch_bounds__(TPB)
cg_persistent(const float* __restrict__ mask, const float* __restrict__ y,
              const float* __restrict__ z, const float* __restrict__ bet,
              const float* __restrict__ rho_p, const float* __restrict__ kern,
              float* __restrict__ x_out, float* __restrict__ ws)
{
    __shared__ float ksh[27];
    __shared__ float dext[36 * 36];
    __shared__ float tsh[3 * 1156];
    __shared__ float m_ring[3][272];
    __shared__ float p_ring[3][272];

    float* rbuf   = ws;
    float* sc     = ws + WS_SC;         // crit[0..101]
    float* sden   = ws + WS_SC + 128;   // denom[0..100]
    unsigned* bar = (unsigned*)(ws + WS_BAR);

    const int tid = threadIdx.x;
    const int T  = blockIdx.x;
    const int bi = T >> 6;
    const int h0 = ((T >> 3) & 7) << 5;
    const int w0 = (T & 7) << 5;

    // ---- population count arrival (poll deferred to overlap with init work)
    unsigned my_xcc = 0, xn = 0, ng = 0; bool agent_loc = false;
    if (tid == 0) {
        unsigned xcc;
        asm volatile("s_getreg_b32 %0, hwreg(HW_REG_XCC_ID)" : "=s"(xcc));
        my_xcc = xcc & 7u;
        __hip_atomic_fetch_add(bar + B_XCNT + 16 * my_xcc, 1u,
                               __ATOMIC_RELAXED, __HIP_MEMORY_SCOPE_AGENT);
        __hip_atomic_fetch_add(bar + B_ICNT, 1u,
                               __ATOMIC_RELAXED, __HIP_MEMORY_SCOPE_AGENT);
    }

    if (tid < 27) ksh[tid] = kern[tid];
    const float rho = rho_p[0];

    int roff[4];
    #pragma unroll
    for (int k = 0; k < 4; ++k) {
        const int e = tid + (k << 8);
        roff[k] = (h0 + (e >> 5)) * W + (w0 + (e & 31));
    }
    float m_[3][4], x_[3][4], r_[3][4], p_[3][4], Ap_[3][4];
    #pragma unroll
    for (int c = 0; c < 3; ++c)
        #pragma unroll
        for (int k = 0; k < 4; ++k)
            m_[c][k] = mask[(bi * 3 + c) * HW + roff[k]];

    for (int t = tid; t < 272; t += TPB) {
        int eh, ew; ring_pos(t, eh, ew);
        const int gh = h0 + eh - 2, gw = w0 + ew - 2;
        const bool valid = (unsigned)gh < (unsigned)H && (unsigned)gw < (unsigned)W;
        #pragma unroll
        for (int c = 0; c < 3; ++c) {
            m_ring[c][t] = valid ? mask[(bi * 3 + c) * HW + gh * W + gw] : 0.f;
            p_ring[c][t] = 0.f;
        }
    }

    // ---- I-a: q0 = PT(P(y)); b = m*q0 + rho*(z-bet); x = b; publish b border
    for (int e = tid; e < 1296; e += TPB) {
        const int eh = e / 36, ew = e - eh * 36;
        const int gh = h0 + eh - 2, gw = w0 + ew - 2;
        dext[e] = ((unsigned)gh < (unsigned)H && (unsigned)gw < (unsigned)W)
                      ? y[bi * HW + gh * W + gw] : 0.f;
    }
    __syncthreads();
    conv_p(dext, tsh, ksh, tid, h0, w0);
    __syncthreads();
    #pragma unroll
    for (int k = 0; k < 4; ++k) {
        const int e = tid + (k << 8);
        const int h = e >> 5, w = e & 31;
        const float q = conv_pt(tsh, ksh, h, w);
        const bool bord = (h < 2) | (h >= 30) | (w < 2) | (w >= 30);
        #pragma unroll
        for (int c = 0; c < 3; ++c) {
            const int gi = (bi * 3 + c) * HW + roff[k];
            const float b = m_[c][k] * q + rho * (z[gi] - bet[gi]);
            x_[c][k] = b;
            if (bord) ST_AG(&rbuf[gi], b);
        }
    }

    // finish population count
    if (tid == 0) {
        const unsigned zz = opaque_zero();
        while (__hip_atomic_fetch_add(bar + B_ICNT, zz, __ATOMIC_RELAXED,
                                      __HIP_MEMORY_SCOPE_AGENT) < (unsigned)NBLK)
            __builtin_amdgcn_s_sleep(16);
        ng = 0;
        #pragma unroll
        for (int i = 0; i < 8; ++i) {
            unsigned c = __hip_atomic_fetch_add(bar + B_XCNT + 16 * i, zz,
                             __ATOMIC_RELAXED, __HIP_MEMORY_SCOPE_AGENT);
            ng += (c > 0u);
        }
        xn = __hip_atomic_fetch_add(bar + B_XCNT + 16 * my_xcc, zz,
                 __ATOMIC_RELAXED, __HIP_MEMORY_SCOPE_AGENT);
        agent_loc = (ng <= 1u);   // safety fallback if XCC grouping degenerate
    }
    unsigned rnd = 1;
    xbar(bar, rnd++, my_xcc, xn, ng, agent_loc);     // b borders visible

    // ---- I-b: d0 = sum m*b (ring from rbuf); Ap0 = A(b); r0 = p0 = b - Ap0
    #pragma unroll
    for (int k = 0; k < 4; ++k) {
        const int e = tid + (k << 8);
        float s = 0.f;
        #pragma unroll
        for (int c = 0; c < 3; ++c) s += m_[c][k] * x_[c][k];
        dext[((e >> 5) + 2) * 36 + (e & 31) + 2] = s;
    }
    for (int t = tid; t < 272; t += TPB) {
        int eh, ew; ring_pos(t, eh, ew);
        const int gh = h0 + eh - 2, gw = w0 + ew - 2;
        float s = 0.f;
        if ((unsigned)gh < (unsigned)H && (unsigned)gw < (unsigned)W) {
            #pragma unroll
            for (int c = 0; c < 3; ++c)
                s += m_ring[c][t] * LD_AG(&rbuf[(bi * 3 + c) * HW + gh * W + gw]);
        }
        dext[eh * 36 + ew] = s;
    }
    __syncthreads();
    conv_p(dext, tsh, ksh, tid, h0, w0);
    __syncthreads();
    float csum0 = 0.f;
    #pragma unroll
    for (int k = 0; k < 4; ++k) {
        const int e = tid + (k << 8);
        const float q = conv_pt(tsh, ksh, e >> 5, e & 31);
        #pragma unroll
        for (int c = 0; c < 3; ++c) {
            const float b = x_[c][k];
            const float rv = b - (rho * b + m_[c][k] * q);
            r_[c][k] = rv; p_[c][k] = rv;
            csum0 += rv * rv;
        }
    }
    block_reduce_atomic(csum0, sc + 0);
    xbar(bar, rnd++, my_xcc, xn, ng, agent_loc);     // all b-ring reads done

    // publish r0 border, then read halo -> p_ring
    #pragma unroll
    for (int k = 0; k < 4; ++k) {
        const int e = tid + (k << 8);
        const int h = e >> 5, w = e & 31;
        if ((h < 2) | (h >= 30) | (w < 2) | (w >= 30)) {
            #pragma unroll
            for (int c = 0; c < 3; ++c)
                ST_AG(&rbuf[(bi * 3 + c) * HW + roff[k]], r_[c][k]);
        }
    }
    xbar(bar, rnd++, my_xcc, xn, ng, agent_loc);     // r0 borders visible
    for (int t = tid; t < 272; t += TPB) {
        int eh, ew; ring_pos(t, eh, ew);
        const int gh = h0 + eh - 2, gw = w0 + ew - 2;
        if ((unsigned)gh < (unsigned)H && (unsigned)gw < (unsigned)W) {
            #pragma unroll
            for (int c = 0; c < 3; ++c)
                p_ring[c][t] = LD_AG(&rbuf[(bi * 3 + c) * HW + gh * W + gw]);
        }
    }

    // ---- CG loop: 2 grid barriers per iteration
    for (int j = 0; j < NITER; ++j) {
        const float critj = LD_AG(sc + j);
        const bool active = critj >= TOL;

        // d_ext fully local (core from registers, ring from p_ring recurrence)
        #pragma unroll
        for (int k = 0; k < 4; ++k) {
            const int e = tid + (k << 8);
            float s = 0.f;
            #pragma unroll
            for (int c = 0; c < 3; ++c) s += m_[c][k] * p_[c][k];
            dext[((e >> 5) + 2) * 36 + (e & 31) + 2] = s;
        }
        for (int t = tid; t < 272; t += TPB) {
            int eh, ew; ring_pos(t, eh, ew);
            float s = 0.f;
            #pragma unroll
            for (int c = 0; c < 3; ++c) s += m_ring[c][t] * p_ring[c][t];
            dext[eh * 36 + ew] = s;
        }
        __syncthreads();
        conv_p(dext, tsh, ksh, tid, h0, w0);
        __syncthreads();
        float dsum = 0.f;
        #pragma unroll
        for (int k = 0; k < 4; ++k) {
            const int e = tid + (k << 8);
            const float q = conv_pt(tsh, ksh, e >> 5, e & 31);
            #pragma unroll
            for (int c = 0; c < 3; ++c) {
                const float ap = rho * p_[c][k] + m_[c][k] * q;
                Ap_[c][k] = ap;
                dsum += p_[c][k] * ap;
            }
        }
        block_reduce_atomic(dsum, sden + j);
        xbar(bar, rnd++, my_xcc, xn, ng, agent_loc);   // denom ready

        const float denom = LD_AG(sden + j);
        const float alpha = critj / (active ? denom : 1.0f);
        float csum = 0.f;
        #pragma unroll
        for (int c = 0; c < 3; ++c)
            #pragma unroll
            for (int k = 0; k < 4; ++k) {
                if (active) {
                    x_[c][k] += alpha * p_[c][k];
                    r_[c][k] -= alpha * Ap_[c][k];
                }
                csum += r_[c][k] * r_[c][k];
            }
        block_reduce_atomic(csum, sc + j + 1);
        #pragma unroll
        for (int k = 0; k < 4; ++k) {                  // publish r border
            const int e = tid + (k << 8);
            const int h = e >> 5, w = e & 31;
            if ((h < 2) | (h >= 30) | (w < 2) | (w >= 30)) {
                #pragma unroll
                for (int c = 0; c < 3; ++c)
                    ST_AG(&rbuf[(bi * 3 + c) * HW + roff[k]], r_[c][k]);
            }
        }
        xbar(bar, rnd++, my_xcc, xn, ng, agent_loc);   // crit + r borders ready

        const float critn = LD_AG(sc + j + 1);
        const float beta = critn / (active ? critj : 1.0f);
        if (active) {
            #pragma unroll
            for (int c = 0; c < 3; ++c)
                #pragma unroll
                for (int k = 0; k < 4; ++k)
                    p_[c][k] = r_[c][k] + beta * p_[c][k];
        }
        for (int t = tid; t < 272; t += TPB) {         // p_ring recurrence
            int eh, ew; ring_pos(t, eh, ew);
            const int gh = h0 + eh - 2, gw = w0 + ew - 2;
            if ((unsigned)gh < (unsigned)H && (unsigned)gw < (unsigned)W) {
                #pragma unroll
                for (int c = 0; c < 3; ++c) {
                    const float rr = LD_AG(&rbuf[(bi * 3 + c) * HW + gh * W + gw]);
                    if (active) p_ring[c][t] = rr + beta * p_ring[c][t];
                }
            }
        }
    }

    #pragma unroll
    for (int c = 0; c < 3; ++c)
        #pragma unroll
        for (int k = 0; k < 4; ++k)
            x_out[(bi * 3 + c) * HW + roff[k]] = x_[c][k];
}

extern "C" void kernel_launch(void* const* d_in, const int* in_sizes, int n_in,
                              void* d_out, int out_size, void* d_ws, size_t ws_size,
                              hipStream_t stream)
{
    const float* mask = (const float*)d_in[0];
    const float* y    = (const float*)d_in[1];
    const float* z    = (const float*)d_in[2];
    const float* bet  = (const float*)d_in[3];
    const float* rho  = (const float*)d_in[4];
    const float* kern = (const float*)d_in[5];
    float* x  = (float*)d_out;
    float* ws = (float*)d_ws;

    // zero scalar slots + barrier state (ws is re-poisoned before every call)
    hipMemsetAsync(ws + WS_SC, 0, 4096, stream);

    void* args[] = { (void*)&mask, (void*)&y, (void*)&z, (void*)&bet,
                     (void*)&rho, (void*)&kern, (void*)&x, (void*)&ws };
    hipLaunchCooperativeKernel((void*)cg_persistent, dim3(NBLK), dim3(TPB),
                               args, 0, stream);
}

// Round 6
// 1464.405 us; speedup vs baseline: 4.3164x; 1.0977x over previous
//
#include <hip/hip_runtime.h>

#define TOL 1e-6f
#define NITER 101
#define H 256
#define W 256
#define HW 65536
#define NBLK 256
#define TPB 256

typedef unsigned long long ull;

// ---- workspace layout (float offsets) ----
#define STRIP_F 768                  // floats per block per buffer (3ch x 256)
#define STRIPBUF (NBLK * STRIP_F)    // 196608 floats per buffer
#define WS_CTRL (2 * STRIPBUF)       // control region starts here
#define CTRL_F 8192                  // 32 KB control region (memset at launch)
// ctrl layout (float offsets within ctrl):
//   gval[256]      @ 0      per-round global value slots (LLC)
//   lval[8][256]   @ 256    per-XCD per-round value slots (L2)
//   uint area      @ 2304:
//     lcnt[x]  @ u+ x*16     (monotonic per-XCD arrival)
//     gcnt     @ u+128       (monotonic leader arrival)
//     icnt     @ u+144       (population sync)
//     xcnt[x]  @ u+160+x*16  (per-XCD population)
//     bcast[x] @ (ull*)(u+320) + x*8   {rnd,val} LLC fan-out lines
//     lbc[x]   @ (ull*)(u+448) + x*8   {rnd,val} per-XCD L2 relay lines

#define LD_AG(p)    __hip_atomic_load((p), __ATOMIC_RELAXED, __HIP_MEMORY_SCOPE_AGENT)
#define ST_AG(p,v)  __hip_atomic_store((p), (v), __ATOMIC_RELAXED, __HIP_MEMORY_SCOPE_AGENT)

// Opaque identity operands: WITHOUT these, InstCombine rewrites
// atomicrmw add p,0 -> load atomic (same scope). A workgroup-scope atomic
// load is served from the spinner's L1 (write-through L1 never sees the
// leader's L2 store) -> stale spin -> HANG. This exact conversion is why
// rounds 4/5 hung while round 3 (opaque operands) ran. RMWs execute at
// >= L2/coherence point and can never be L1-stale.
__device__ __forceinline__ unsigned opq0u() {
    unsigned z; asm volatile("s_mov_b32 %0, 0" : "=s"(z)); return z;
}
__device__ __forceinline__ ull opq0ull() {
    return ((ull)opq0u() << 32) | (ull)opq0u();
}
__device__ __forceinline__ float opq0f() { return __uint_as_float(opq0u()); }

// ---------------------------------------------------------------------------
// fused reduce + broadcast + barrier. Returns grid-wide sum of v to ALL blocks.
// xn = blocks on my XCD, ng = #XCDs present (thread0-only values).
// ---------------------------------------------------------------------------
__device__ __forceinline__ float frb(float v, unsigned rnd, float* ctrl,
                                     unsigned my_xcc, unsigned xn, unsigned ng) {
    __shared__ float red_[8];
    asm volatile("s_waitcnt vmcnt(0)" ::: "memory");   // drain strip stores etc.
    #pragma unroll
    for (int off = 32; off; off >>= 1) v += __shfl_down(v, off, 64);
    const int lane = threadIdx.x & 63, wid = threadIdx.x >> 6;
    if (lane == 0) red_[wid] = v;
    __syncthreads();
    if (threadIdx.x == 0) {
        const float part = red_[0] + red_[1] + red_[2] + red_[3];
        float* lval = ctrl + 256 + my_xcc * 256;
        float* gval = ctrl;
        unsigned* cu = (unsigned*)(ctrl + 2304);
        ull* bcast = (ull*)(cu + 320);
        ull* lbc   = (ull*)(cu + 448);
        // partial -> XCD L2 slot, drain, then arrival count
        __hip_atomic_fetch_add(lval + rnd, part, __ATOMIC_RELAXED, __HIP_MEMORY_SCOPE_WORKGROUP);
        asm volatile("s_waitcnt vmcnt(0)" ::: "memory");
        unsigned a = __hip_atomic_fetch_add(cu + my_xcc * 16, 1u,
                         __ATOMIC_RELAXED, __HIP_MEMORY_SCOPE_WORKGROUP);
        ull pk;
        if (a == rnd * xn - 1u) {                       // XCD leader (last arriver)
            float lsum = __hip_atomic_fetch_add(lval + rnd, opq0f(),
                             __ATOMIC_RELAXED, __HIP_MEMORY_SCOPE_WORKGROUP);
            __hip_atomic_fetch_add(gval + rnd, lsum,
                                   __ATOMIC_RELAXED, __HIP_MEMORY_SCOPE_AGENT);
            asm volatile("s_waitcnt vmcnt(0)" ::: "memory");
            unsigned g = __hip_atomic_fetch_add(cu + 128, 1u,
                             __ATOMIC_RELAXED, __HIP_MEMORY_SCOPE_AGENT);
            if (g == rnd * ng - 1u) {                   // global master
                float tot = __hip_atomic_fetch_add(gval + rnd, opq0f(),
                                __ATOMIC_RELAXED, __HIP_MEMORY_SCOPE_AGENT);
                pk = ((ull)rnd << 32) | (ull)__float_as_uint(tot);
                #pragma unroll
                for (int xx = 0; xx < 8; ++xx)
                    __hip_atomic_store(bcast + xx * 8, pk,
                                       __ATOMIC_RELAXED, __HIP_MEMORY_SCOPE_AGENT);
            } else {
                for (;;) {
                    pk = __hip_atomic_fetch_add(bcast + my_xcc * 8, opq0ull(),
                             __ATOMIC_RELAXED, __HIP_MEMORY_SCOPE_AGENT);
                    if ((unsigned)(pk >> 32) >= rnd) break;
                    __builtin_amdgcn_s_sleep(2);
                }
            }
            __hip_atomic_store(lbc + my_xcc * 8, pk,
                               __ATOMIC_RELAXED, __HIP_MEMORY_SCOPE_WORKGROUP);
        } else {
            for (;;) {
                pk = __hip_atomic_fetch_add(lbc + my_xcc * 8, opq0ull(),
                         __ATOMIC_RELAXED, __HIP_MEMORY_SCOPE_WORKGROUP);
                if ((unsigned)(pk >> 32) >= rnd) break;
                __builtin_amdgcn_s_sleep(1);
            }
        }
        red_[4] = __uint_as_float((unsigned)(pk & 0xffffffffull));
    }
    __syncthreads();
    return red_[4];
}

// halo ring (36x36 minus 32x32 core): 272 positions
__device__ __forceinline__ void ring_pos(int t, int& eh, int& ew) {
    if (t < 72)       { eh = t / 36;                 ew = t - (t / 36) * 36; }
    else if (t < 144) { const int u = t - 72;  eh = 34 + u / 36; ew = u - (u / 36) * 36; }
    else              { const int u = t - 144; eh = 2 + (u >> 2);
                        const int c2 = u & 3;  ew = (c2 < 2) ? c2 : c2 + 32; }
}

// conv P: dext[36x36] -> tsh[3][34x34], cropped to image (zeros outside)
__device__ __forceinline__ void conv_p(const float* dext, float* tsh,
                                       const float* ksh, int tid, int h0, int w0) {
    for (int e = tid; e < 1156; e += TPB) {
        const int th = e / 34, tw = e - th * 34;
        const int gh = h0 + th - 1, gw = w0 + tw - 1;
        float t0 = 0.f, t1 = 0.f, t2 = 0.f;
        if ((unsigned)gh < (unsigned)H && (unsigned)gw < (unsigned)W) {
            #pragma unroll
            for (int i = 0; i < 3; ++i)
                #pragma unroll
                for (int j = 0; j < 3; ++j) {
                    const float v = dext[(th + i) * 36 + tw + j];
                    t0 += v * ksh[i * 3 + j];
                    t1 += v * ksh[9 + i * 3 + j];
                    t2 += v * ksh[18 + i * 3 + j];
                }
        }
        tsh[e] = t0; tsh[1156 + e] = t1; tsh[2312 + e] = t2;
    }
}

__device__ __forceinline__ float conv_pt(const float* tsh, const float* ksh, int h, int w) {
    float q = 0.f;
    #pragma unroll
    for (int o = 0; o < 3; ++o)
        #pragma unroll
        for (int i = 0; i < 3; ++i)
            #pragma unroll
            for (int j = 0; j < 3; ++j)
                q += tsh[o * 1156 + (h + i) * 34 + (w + j)] * ksh[o * 9 + (2 - i) * 3 + (2 - j)];
    return q;
}

extern "C" __global__ void __launch_bounds__(TPB)
cg_persistent(const float* __restrict__ mask, const float* __restrict__ y,
              const float* __restrict__ z, const float* __restrict__ bet,
              const float* __restrict__ rho_p, const float* __restrict__ kern,
              float* __restrict__ x_out, float* __restrict__ ws)
{
    __shared__ float ksh[27];
    __shared__ float dext[36 * 36];
    __shared__ float tsh[3 * 1156];
    __shared__ float m_ring[3][272];
    __shared__ float p_ring[3][272];
    __shared__ float sstage[STRIP_F];
    __shared__ int   ringsrc[272];

    float* strip = ws;                       // 2 buffers
    float* ctrl  = ws + WS_CTRL;

    const int tid = threadIdx.x;
    const int T  = blockIdx.x;
    const int bi = T >> 6;
    const int h0 = ((T >> 3) & 7) << 5;
    const int w0 = (T & 7) << 5;

    // XCC id (uniform sgpr read)
    unsigned xcc_raw;
    asm volatile("s_getreg_b32 %0, hwreg(HW_REG_XCC_ID)" : "=s"(xcc_raw));
    const unsigned my_xcc = xcc_raw & 7u;

    // population arrival (poll deferred to overlap with init compute)
    unsigned xn = 0, ng = 0;
    unsigned* cu = (unsigned*)(ctrl + 2304);
    if (tid == 0) {
        __hip_atomic_fetch_add(cu + 160 + 16 * my_xcc, 1u,
                               __ATOMIC_RELAXED, __HIP_MEMORY_SCOPE_AGENT);
        __hip_atomic_fetch_add(cu + 144, 1u,
                               __ATOMIC_RELAXED, __HIP_MEMORY_SCOPE_AGENT);
    }

    if (tid < 27) ksh[tid] = kern[tid];
    const float rho = rho_p[0];

    int roff[4];
    #pragma unroll
    for (int k = 0; k < 4; ++k) {
        const int e = tid + (k << 8);
        roff[k] = (h0 + (e >> 5)) * W + (w0 + (e & 31));
    }
    float m_[3][4], x_[3][4], r_[3][4], p_[3][4], Ap_[3][4];
    #pragma unroll
    for (int c = 0; c < 3; ++c)
        #pragma unroll
        for (int k = 0; k < 4; ++k)
            m_[c][k] = mask[(bi * 3 + c) * HW + roff[k]];

    // m_ring + iteration-invariant ring -> neighbor-strip index table
    for (int t = tid; t < 272; t += TPB) {
        int eh, ew; ring_pos(t, eh, ew);
        const int gh = h0 + eh - 2, gw = w0 + ew - 2;
        const bool valid = (unsigned)gh < (unsigned)H && (unsigned)gw < (unsigned)W;
        int src = -1;
        if (valid) {
            const int tr = gh >> 5, tc = gw >> 5;
            const int Tn = (bi << 6) | (tr << 3) | tc;
            const int lh = gh & 31, lw = gw & 31;
            int idx;
            if (tr != (h0 >> 5)) idx = (lh >= 30) ? 64 + (lh - 30) * 32 + lw : lh * 32 + lw;
            else                 idx = (lw >= 30) ? 192 + lh * 2 + (lw - 30) : 128 + lh * 2 + lw;
            src = Tn * STRIP_F + idx;
        }
        ringsrc[t] = src;
        #pragma unroll
        for (int c = 0; c < 3; ++c) {
            m_ring[c][t] = valid ? mask[(bi * 3 + c) * HW + gh * W + gw] : 0.f;
            p_ring[c][t] = 0.f;
        }
    }

    // ---- I-a: q0 = PT(P(y)); b = m*q0 + rho*(z-bet); x = b; publish b strips
    for (int e = tid; e < 1296; e += TPB) {
        const int eh = e / 36, ew = e - eh * 36;
        const int gh = h0 + eh - 2, gw = w0 + ew - 2;
        dext[e] = ((unsigned)gh < (unsigned)H && (unsigned)gw < (unsigned)W)
                      ? y[bi * HW + gh * W + gw] : 0.f;
    }
    __syncthreads();
    conv_p(dext, tsh, ksh, tid, h0, w0);
    __syncthreads();
    #pragma unroll
    for (int k = 0; k < 4; ++k) {
        const int e = tid + (k << 8);
        const int h = e >> 5, w = e & 31;
        const float q = conv_pt(tsh, ksh, h, w);
        #pragma unroll
        for (int c = 0; c < 3; ++c) {
            const int gi = (bi * 3 + c) * HW + roff[k];
            const float b = m_[c][k] * q + rho * (z[gi] - bet[gi]);
            x_[c][k] = b;
            if (h < 2)   sstage[c * 256 + h * 32 + w] = b;
            if (h >= 30) sstage[c * 256 + 64 + (h - 30) * 32 + w] = b;
            if (w < 2)   sstage[c * 256 + 128 + h * 2 + w] = b;
            if (w >= 30) sstage[c * 256 + 192 + h * 2 + (w - 30)] = b;
        }
    }
    __syncthreads();
    for (int t = tid; t < STRIP_F; t += TPB)
        ST_AG(strip + T * STRIP_F + t, sstage[t]);

    // finish population count -> xn, ng (opaque RMW polls)
    if (tid == 0) {
        while (__hip_atomic_fetch_add(cu + 144, opq0u(), __ATOMIC_RELAXED,
                                      __HIP_MEMORY_SCOPE_AGENT) < (unsigned)NBLK)
            __builtin_amdgcn_s_sleep(32);
        ng = 0;
        #pragma unroll
        for (int i = 0; i < 8; ++i) {
            unsigned c = __hip_atomic_fetch_add(cu + 160 + 16 * i, opq0u(),
                             __ATOMIC_RELAXED, __HIP_MEMORY_SCOPE_AGENT);
            ng += (c > 0u);
        }
        xn = __hip_atomic_fetch_add(cu + 160 + 16 * my_xcc, opq0u(),
                 __ATOMIC_RELAXED, __HIP_MEMORY_SCOPE_AGENT);
    }
    unsigned rnd = 1;
    frb(0.f, rnd++, ctrl, my_xcc, xn, ng);           // b strips visible

    // ---- I-b: d0 = sum m*b; Ap0 = A(b); r0 = p0 = b - Ap0; crit0; publish r0
    #pragma unroll
    for (int k = 0; k < 4; ++k) {
        const int e = tid + (k << 8);
        float s = 0.f;
        #pragma unroll
        for (int c = 0; c < 3; ++c) s += m_[c][k] * x_[c][k];
        dext[((e >> 5) + 2) * 36 + (e & 31) + 2] = s;
    }
    for (int t = tid; t < 272; t += TPB) {
        int eh, ew; ring_pos(t, eh, ew);
        const int src = ringsrc[t];
        float s = 0.f;
        if (src >= 0) {
            #pragma unroll
            for (int c = 0; c < 3; ++c)
                s += m_ring[c][t] * LD_AG(strip + src + c * 256);
        }
        dext[eh * 36 + ew] = s;
    }
    __syncthreads();
    conv_p(dext, tsh, ksh, tid, h0, w0);
    __syncthreads();
    float csum0 = 0.f;
    #pragma unroll
    for (int k = 0; k < 4; ++k) {
        const int e = tid + (k << 8);
        const int h = e >> 5, w = e & 31;
        const float q = conv_pt(tsh, ksh, h, w);
        #pragma unroll
        for (int c = 0; c < 3; ++c) {
            const float b = x_[c][k];
            const float rv = b - (rho * b + m_[c][k] * q);
            r_[c][k] = rv; p_[c][k] = rv;
            csum0 += rv * rv;
            if (h < 2)   sstage[c * 256 + h * 32 + w] = rv;
            if (h >= 30) sstage[c * 256 + 64 + (h - 30) * 32 + w] = rv;
            if (w < 2)   sstage[c * 256 + 128 + h * 2 + w] = rv;
            if (w >= 30) sstage[c * 256 + 192 + h * 2 + (w - 30)] = rv;
        }
    }
    __syncthreads();
    for (int t = tid; t < STRIP_F; t += TPB)
        ST_AG(strip + STRIPBUF + T * STRIP_F + t, sstage[t]);

    float critj = frb(csum0, rnd++, ctrl, my_xcc, xn, ng);   // r0 strips visible

    // p_ring <- r0 halo
    for (int t = tid; t < 272; t += TPB) {
        const int src = ringsrc[t];
        if (src >= 0) {
            #pragma unroll
            for (int c = 0; c < 3; ++c)
                p_ring[c][t] = LD_AG(strip + STRIPBUF + src + c * 256);
        }
    }

    // ---- CG loop: 2 frb per iteration
    for (int j = 0; j < NITER; ++j) {
        const bool active = critj >= TOL;

        // dext fully local (core regs + ring recurrence)
        #pragma unroll
        for (int k = 0; k < 4; ++k) {
            const int e = tid + (k << 8);
            float s = 0.f;
            #pragma unroll
            for (int c = 0; c < 3; ++c) s += m_[c][k] * p_[c][k];
            dext[((e >> 5) + 2) * 36 + (e & 31) + 2] = s;
        }
        for (int t = tid; t < 272; t += TPB) {
            int eh, ew; ring_pos(t, eh, ew);
            float s = 0.f;
            #pragma unroll
            for (int c = 0; c < 3; ++c) s += m_ring[c][t] * p_ring[c][t];
            dext[eh * 36 + ew] = s;
        }
        __syncthreads();
        conv_p(dext, tsh, ksh, tid, h0, w0);
        __syncthreads();
        float dsum = 0.f;
        #pragma unroll
        for (int k = 0; k < 4; ++k) {
            const int e = tid + (k << 8);
            const float q = conv_pt(tsh, ksh, e >> 5, e & 31);
            #pragma unroll
            for (int c = 0; c < 3; ++c) {
                const float ap = rho * p_[c][k] + m_[c][k] * q;
                Ap_[c][k] = ap;
                dsum += p_[c][k] * ap;
            }
        }
        const float denom = frb(dsum, rnd++, ctrl, my_xcc, xn, ng);

        const float alpha = critj / (active ? denom : 1.0f);
        float csum = 0.f;
        #pragma unroll
        for (int c = 0; c < 3; ++c)
            #pragma unroll
            for (int k = 0; k < 4; ++k) {
                if (active) {
                    x_[c][k] += alpha * p_[c][k];
                    r_[c][k] -= alpha * Ap_[c][k];
                }
                csum += r_[c][k] * r_[c][k];
            }
        // stage + publish r strips (double-buffered by parity)
        #pragma unroll
        for (int k = 0; k < 4; ++k) {
            const int e = tid + (k << 8);
            const int h = e >> 5, w = e & 31;
            #pragma unroll
            for (int c = 0; c < 3; ++c) {
                const float rv = r_[c][k];
                if (h < 2)   sstage[c * 256 + h * 32 + w] = rv;
                if (h >= 30) sstage[c * 256 + 64 + (h - 30) * 32 + w] = rv;
                if (w < 2)   sstage[c * 256 + 128 + h * 2 + w] = rv;
                if (w >= 30) sstage[c * 256 + 192 + h * 2 + (w - 30)] = rv;
            }
        }
        __syncthreads();
        float* gb = strip + (j & 1) * STRIPBUF;
        for (int t = tid; t < STRIP_F; t += TPB)
            ST_AG(gb + T * STRIP_F + t, sstage[t]);

        const float critn = frb(csum, rnd++, ctrl, my_xcc, xn, ng);

        const float beta = critn / (active ? critj : 1.0f);
        if (active) {
            #pragma unroll
            for (int c = 0; c < 3; ++c)
                #pragma unroll
                for (int k = 0; k < 4; ++k)
                    p_[c][k] = r_[c][k] + beta * p_[c][k];
        }
        for (int t = tid; t < 272; t += TPB) {
            const int src = ringsrc[t];
            if (src >= 0) {
                #pragma unroll
                for (int c = 0; c < 3; ++c) {
                    const float rr = LD_AG(gb + src + c * 256);
                    if (active) p_ring[c][t] = rr + beta * p_ring[c][t];
                }
            }
        }
        critj = critn;
    }

    #pragma unroll
    for (int c = 0; c < 3; ++c)
        #pragma unroll
        for (int k = 0; k < 4; ++k)
            x_out[(bi * 3 + c) * HW + roff[k]] = x_[c][k];
}

extern "C" void kernel_launch(void* const* d_in, const int* in_sizes, int n_in,
                              void* d_out, int out_size, void* d_ws, size_t ws_size,
                              hipStream_t stream)
{
    const float* mask = (const float*)d_in[0];
    const float* y    = (const float*)d_in[1];
    const float* z    = (const float*)d_in[2];
    const float* bet  = (const float*)d_in[3];
    const float* rho  = (const float*)d_in[4];
    const float* kern = (const float*)d_in[5];
    float* x  = (float*)d_out;
    float* ws = (float*)d_ws;

    // zero value slots / counters / bcast lines (ws re-poisoned every call)
    hipMemsetAsync(ws + WS_CTRL, 0, CTRL_F * sizeof(float), stream);

    void* args[] = { (void*)&mask, (void*)&y, (void*)&z, (void*)&bet,
                     (void*)&rho, (void*)&kern, (void*)&x, (void*)&ws };
    hipLaunchCooperativeKernel((void*)cg_persistent, dim3(NBLK), dim3(TPB),
                               args, 0, stream);
}

// Round 7
// 1313.652 us; speedup vs baseline: 4.8118x; 1.1148x over previous
//
#include <hip/hip_runtime.h>

#define TOL 1e-6f
#define NITER 101
#define H 256
#define W 256
#define HW 65536
#define NBLK 256
#define TPB 256

typedef unsigned long long ull;

// ---- workspace layout (float offsets) ----
#define STRIP_F 768                  // floats per block per buffer (3ch x 256)
#define STRIPBUF (NBLK * STRIP_F)
#define WS_CTRL (2 * STRIPBUF)
#define CTRL_F 8192

#define LD_AG(p)    __hip_atomic_load((p), __ATOMIC_RELAXED, __HIP_MEMORY_SCOPE_AGENT)
#define ST_AG(p,v)  __hip_atomic_store((p), (v), __ATOMIC_RELAXED, __HIP_MEMORY_SCOPE_AGENT)

// Opaque identity operands: WITHOUT these, InstCombine rewrites
// atomicrmw add p,0 -> load atomic (same scope); a workgroup-scope atomic
// load is served from the spinner's stale L1 -> infinite spin (the R4/R5
// hang). RMWs execute at >= L2 and can never be L1-stale.
__device__ __forceinline__ unsigned opq0u() {
    unsigned z; asm volatile("s_mov_b32 %0, 0" : "=s"(z)); return z;
}
__device__ __forceinline__ ull opq0ull() {
    return ((ull)opq0u() << 32) | (ull)opq0u();
}
__device__ __forceinline__ float opq0f() { return __uint_as_float(opq0u()); }

// ---------------------------------------------------------------------------
// fused reduce + broadcast + barrier (PROVEN in R6 — unchanged).
// ---------------------------------------------------------------------------
__device__ __forceinline__ float frb(float v, unsigned rnd, float* ctrl,
                                     unsigned my_xcc, unsigned xn, unsigned ng) {
    __shared__ float red_[8];
    asm volatile("s_waitcnt vmcnt(0)" ::: "memory");
    #pragma unroll
    for (int off = 32; off; off >>= 1) v += __shfl_down(v, off, 64);
    const int lane = threadIdx.x & 63, wid = threadIdx.x >> 6;
    if (lane == 0) red_[wid] = v;
    __syncthreads();
    if (threadIdx.x == 0) {
        const float part = red_[0] + red_[1] + red_[2] + red_[3];
        float* lval = ctrl + 256 + my_xcc * 256;
        float* gval = ctrl;
        unsigned* cu = (unsigned*)(ctrl + 2304);
        ull* bcast = (ull*)(cu + 320);
        ull* lbc   = (ull*)(cu + 448);
        __hip_atomic_fetch_add(lval + rnd, part, __ATOMIC_RELAXED, __HIP_MEMORY_SCOPE_WORKGROUP);
        asm volatile("s_waitcnt vmcnt(0)" ::: "memory");
        unsigned a = __hip_atomic_fetch_add(cu + my_xcc * 16, 1u,
                         __ATOMIC_RELAXED, __HIP_MEMORY_SCOPE_WORKGROUP);
        ull pk;
        if (a == rnd * xn - 1u) {                       // XCD leader (last arriver)
            float lsum = __hip_atomic_fetch_add(lval + rnd, opq0f(),
                             __ATOMIC_RELAXED, __HIP_MEMORY_SCOPE_WORKGROUP);
            __hip_atomic_fetch_add(gval + rnd, lsum,
                                   __ATOMIC_RELAXED, __HIP_MEMORY_SCOPE_AGENT);
            asm volatile("s_waitcnt vmcnt(0)" ::: "memory");
            unsigned g = __hip_atomic_fetch_add(cu + 128, 1u,
                             __ATOMIC_RELAXED, __HIP_MEMORY_SCOPE_AGENT);
            if (g == rnd * ng - 1u) {                   // global master
                float tot = __hip_atomic_fetch_add(gval + rnd, opq0f(),
                                __ATOMIC_RELAXED, __HIP_MEMORY_SCOPE_AGENT);
                pk = ((ull)rnd << 32) | (ull)__float_as_uint(tot);
                #pragma unroll
                for (int xx = 0; xx < 8; ++xx)
                    __hip_atomic_store(bcast + xx * 8, pk,
                                       __ATOMIC_RELAXED, __HIP_MEMORY_SCOPE_AGENT);
            } else {
                for (;;) {
                    pk = __hip_atomic_fetch_add(bcast + my_xcc * 8, opq0ull(),
                             __ATOMIC_RELAXED, __HIP_MEMORY_SCOPE_AGENT);
                    if ((unsigned)(pk >> 32) >= rnd) break;
                    __builtin_amdgcn_s_sleep(2);
                }
            }
            __hip_atomic_store(lbc + my_xcc * 8, pk,
                               __ATOMIC_RELAXED, __HIP_MEMORY_SCOPE_WORKGROUP);
        } else {
            for (;;) {
                pk = __hip_atomic_fetch_add(lbc + my_xcc * 8, opq0ull(),
                         __ATOMIC_RELAXED, __HIP_MEMORY_SCOPE_WORKGROUP);
                if ((unsigned)(pk >> 32) >= rnd) break;
                __builtin_amdgcn_s_sleep(1);
            }
        }
        red_[4] = __uint_as_float((unsigned)(pk & 0xffffffffull));
    }
    __syncthreads();
    return red_[4];
}

// halo ring (36x36 minus 32x32 core): 272 positions
__device__ __forceinline__ void ring_pos(int t, int& eh, int& ew) {
    if (t < 72)       { eh = t / 36;                 ew = t - (t / 36) * 36; }
    else if (t < 144) { const int u = t - 72;  eh = 34 + u / 36; ew = u - (u / 36) * 36; }
    else              { const int u = t - 144; eh = 2 + (u >> 2);
                        const int c2 = u & 3;  ew = (c2 < 2) ? c2 : c2 + 32; }
}

// ---------------------------------------------------------------------------
// composite PT(P(.)) as 25-tap K2 over dext + border fixups.
// thread owns outputs (row, wb..wb+3); dext core at [+2][+2].
// ---------------------------------------------------------------------------
__device__ __forceinline__ float4 conv_k2(const float* dext, int row, int wb,
                                          int h0, int w0,
                                          const float* K2sh,
                                          const float* Ctop, const float* Cbot,
                                          const float* CLf, const float* CLt, const float* CLb,
                                          const float* CRf, const float* CRt, const float* CRb)
{
    float q[4] = {0.f, 0.f, 0.f, 0.f};
    float w2s[8], cL[5], cR[5];
    const float* base = dext + row * 36 + wb;
    #pragma unroll
    for (int A = 0; A < 5; ++A) {
        const float4 lo = *(const float4*)(base + A * 36);
        const float4 hi = *(const float4*)(base + A * 36 + 4);
        const float w8[8] = {lo.x, lo.y, lo.z, lo.w, hi.x, hi.y, hi.z, hi.w};
        #pragma unroll
        for (int cc = 0; cc < 4; ++cc) {
            float s = q[cc];
            #pragma unroll
            for (int Bq = 0; Bq < 5; ++Bq)
                s += K2sh[A * 5 + Bq] * w8[cc + Bq];
            q[cc] = s;
        }
        if (A == 2) {
            #pragma unroll
            for (int u = 0; u < 8; ++u) w2s[u] = w8[u];
        }
        cL[A] = w8[2]; cR[A] = w8[5];
    }
    const int gh = h0 + row, gwb = w0 + wb;
    if (gh == 0) {
        #pragma unroll
        for (int cc = 0; cc < 4; ++cc)
            #pragma unroll
            for (int Bq = 0; Bq < 5; ++Bq)
                q[cc] -= Ctop[Bq] * w2s[cc + Bq];
    }
    if (gh == 255) {
        #pragma unroll
        for (int cc = 0; cc < 4; ++cc)
            #pragma unroll
            for (int Bq = 0; Bq < 5; ++Bq)
                q[cc] -= Cbot[Bq] * w2s[cc + Bq];
    }
    if (gwb == 0) {
        const float* C = (gh == 0) ? CLt : ((gh == 255) ? CLb : CLf);
        #pragma unroll
        for (int A = 0; A < 5; ++A) q[0] -= C[A] * cL[A];
    }
    if (gwb == 252) {
        const float* C = (gh == 0) ? CRt : ((gh == 255) ? CRb : CRf);
        #pragma unroll
        for (int A = 0; A < 5; ++A) q[3] -= C[A] * cR[A];
    }
    return make_float4(q[0], q[1], q[2], q[3]);
}

extern "C" __global__ void __launch_bounds__(TPB)
cg_persistent(const float* __restrict__ mask, const float* __restrict__ y,
              const float* __restrict__ z, const float* __restrict__ bet,
              const float* __restrict__ rho_p, const float* __restrict__ kern,
              float* __restrict__ x_out, float* __restrict__ ws)
{
    __shared__ float ksh[27];
    __shared__ __align__(16) float dext[36 * 36];
    __shared__ float m_ring[3][272];
    __shared__ float p_ring[3][272];
    __shared__ float sstage[STRIP_F];
    __shared__ int   ringsrc[272];
    __shared__ float K2sh[25];
    __shared__ float Ctop[5], Cbot[5];
    __shared__ float CLf[5], CLt[5], CLb[5], CRf[5], CRt[5], CRb[5];

    float* strip = ws;
    float* ctrl  = ws + WS_CTRL;

    const int tid = threadIdx.x;
    const int T  = blockIdx.x;
    const int bi = T >> 6;
    const int h0 = ((T >> 3) & 7) << 5;
    const int w0 = (T & 7) << 5;
    const int row = tid >> 3;
    const int wb  = (tid & 7) << 2;
    const int roffb = (h0 + row) * W + (w0 + wb);

    unsigned xcc_raw;
    asm volatile("s_getreg_b32 %0, hwreg(HW_REG_XCC_ID)" : "=s"(xcc_raw));
    const unsigned my_xcc = xcc_raw & 7u;

    unsigned xn = 0, ng = 0;
    unsigned* cu = (unsigned*)(ctrl + 2304);
    if (tid == 0) {
        __hip_atomic_fetch_add(cu + 160 + 16 * my_xcc, 1u,
                               __ATOMIC_RELAXED, __HIP_MEMORY_SCOPE_AGENT);
        __hip_atomic_fetch_add(cu + 144, 1u,
                               __ATOMIC_RELAXED, __HIP_MEMORY_SCOPE_AGENT);
    }

    if (tid < 27) ksh[tid] = kern[tid];
    const float rho = rho_p[0];

    float m_[3][4], x_[3][4], r_[3][4], p_[3][4], Ap_[3][4];
    #pragma unroll
    for (int c = 0; c < 3; ++c) {
        const float4 mv = *(const float4*)(mask + (bi * 3 + c) * HW + roffb);
        m_[c][0] = mv.x; m_[c][1] = mv.y; m_[c][2] = mv.z; m_[c][3] = mv.w;
    }

    // m_ring + iteration-invariant ring -> neighbor-strip index table
    for (int t = tid; t < 272; t += TPB) {
        int eh, ew; ring_pos(t, eh, ew);
        const int gh = h0 + eh - 2, gw = w0 + ew - 2;
        const bool valid = (unsigned)gh < (unsigned)H && (unsigned)gw < (unsigned)W;
        int src = -1;
        if (valid) {
            const int tr = gh >> 5, tc = gw >> 5;
            const int Tn = (bi << 6) | (tr << 3) | tc;
            const int lh = gh & 31, lw = gw & 31;
            int idx;
            if (tr != (h0 >> 5)) idx = (lh >= 30) ? 64 + (lh - 30) * 32 + lw : lh * 32 + lw;
            else                 idx = (lw >= 30) ? 192 + lh * 2 + (lw - 30) : 128 + lh * 2 + lw;
            src = Tn * STRIP_F + idx;
        }
        ringsrc[t] = src;
        #pragma unroll
        for (int c = 0; c < 3; ++c) {
            m_ring[c][t] = valid ? mask[(bi * 3 + c) * HW + gh * W + gw] : 0.f;
            p_ring[c][t] = 0.f;
        }
    }

    // ---- I-a: fill dext from y
    for (int e = tid; e < 1296; e += TPB) {
        const int eh = e / 36, ew = e - eh * 36;
        const int gh = h0 + eh - 2, gw = w0 + ew - 2;
        dext[e] = ((unsigned)gh < (unsigned)H && (unsigned)gw < (unsigned)W)
                      ? y[bi * HW + gh * W + gw] : 0.f;
    }
    __syncthreads();

    // ---- generate composite tables (ksh visible after sync above)
    if (tid < 25) {
        const int A = tid / 5, Bq = tid % 5;
        float s = 0.f;
        for (int o = 0; o < 3; ++o)
            for (int i = (A > 2 ? A - 2 : 0); i <= (A < 2 ? A : 2); ++i)
                for (int j = (Bq > 2 ? Bq - 2 : 0); j <= (Bq < 2 ? Bq : 2); ++j)
                    s += ksh[o * 9 + (A - i) * 3 + (Bq - j)] * ksh[o * 9 + (2 - i) * 3 + (2 - j)];
        K2sh[tid] = s;
    } else if (tid < 35) {
        const int Bq = (tid - 25) % 5;
        const int krow = (tid < 30) ? 6 : 0;   // Ctop: k row 2; Cbot: k row 0
        float s = 0.f;
        for (int o = 0; o < 3; ++o)
            for (int j = (Bq > 2 ? Bq - 2 : 0); j <= (Bq < 2 ? Bq : 2); ++j)
                s += ksh[o * 9 + krow + (Bq - j)] * ksh[o * 9 + krow + (2 - j)];
        if (tid < 30) Ctop[Bq] = s; else Cbot[Bq] = s;
    } else if (tid < 65) {
        const int u = tid - 35;        // 0..29: [L/R][variant][A]
        const int side = u / 15;       // 0=L(col 2), 1=R(col 0)
        const int v = (u % 15) / 5;    // 0=full,1=top(i>=1),2=bot(i<=1)
        const int A = u % 5;
        const int kcol = side ? 0 : 2;
        int ilo = (A > 2 ? A - 2 : 0), ihi = (A < 2 ? A : 2);
        if (v == 1 && ilo < 1) ilo = 1;
        if (v == 2 && ihi > 1) ihi = 1;
        float s = 0.f;
        for (int o = 0; o < 3; ++o)
            for (int i = ilo; i <= ihi; ++i)
                s += ksh[o * 9 + (A - i) * 3 + kcol] * ksh[o * 9 + (2 - i) * 3 + kcol];
        float* dst = side ? (v == 0 ? CRf : v == 1 ? CRt : CRb)
                          : (v == 0 ? CLf : v == 1 ? CLt : CLb);
        dst[A] = s;
    }
    __syncthreads();

    // q0 = PT(P(y)); b = m*q0 + rho*(z-bet); x = b; stage b borders
    {
        const float4 qv = conv_k2(dext, row, wb, h0, w0, K2sh, Ctop, Cbot,
                                  CLf, CLt, CLb, CRf, CRt, CRb);
        const float qa[4] = {qv.x, qv.y, qv.z, qv.w};
        #pragma unroll
        for (int c = 0; c < 3; ++c) {
            const int gi = (bi * 3 + c) * HW + roffb;
            const float4 zv = *(const float4*)(z + gi);
            const float4 bv = *(const float4*)(bet + gi);
            const float zz[4] = {zv.x, zv.y, zv.z, zv.w};
            const float bb[4] = {bv.x, bv.y, bv.z, bv.w};
            #pragma unroll
            for (int cc = 0; cc < 4; ++cc)
                x_[c][cc] = m_[c][cc] * qa[cc] + rho * (zz[cc] - bb[cc]);
        }
    }
    #pragma unroll
    for (int c = 0; c < 3; ++c) {
        if (row < 2) {
            #pragma unroll
            for (int cc = 0; cc < 4; ++cc) sstage[c * 256 + row * 32 + wb + cc] = x_[c][cc];
        }
        if (row >= 30) {
            #pragma unroll
            for (int cc = 0; cc < 4; ++cc) sstage[c * 256 + 64 + (row - 30) * 32 + wb + cc] = x_[c][cc];
        }
        if (wb == 0)  { sstage[c * 256 + 128 + row * 2]     = x_[c][0];
                        sstage[c * 256 + 128 + row * 2 + 1] = x_[c][1]; }
        if (wb == 28) { sstage[c * 256 + 192 + row * 2]     = x_[c][2];
                        sstage[c * 256 + 192 + row * 2 + 1] = x_[c][3]; }
    }
    __syncthreads();
    for (int t = tid; t < STRIP_F; t += TPB)
        ST_AG(strip + T * STRIP_F + t, sstage[t]);

    // finish population count -> xn, ng (opaque RMW polls)
    if (tid == 0) {
        while (__hip_atomic_fetch_add(cu + 144, opq0u(), __ATOMIC_RELAXED,
                                      __HIP_MEMORY_SCOPE_AGENT) < (unsigned)NBLK)
            __builtin_amdgcn_s_sleep(32);
        ng = 0;
        #pragma unroll
        for (int i = 0; i < 8; ++i) {
            unsigned c = __hip_atomic_fetch_add(cu + 160 + 16 * i, opq0u(),
                             __ATOMIC_RELAXED, __HIP_MEMORY_SCOPE_AGENT);
            ng += (c > 0u);
        }
        xn = __hip_atomic_fetch_add(cu + 160 + 16 * my_xcc, opq0u(),
                 __ATOMIC_RELAXED, __HIP_MEMORY_SCOPE_AGENT);
    }
    unsigned rnd = 1;
    frb(0.f, rnd++, ctrl, my_xcc, xn, ng);           // b strips visible

    // ---- I-b: d0 = sum m*b; Ap0 = A(b); r0 = p0 = b - Ap0; crit0; publish r0
    {
        float* dp = dext + (row + 2) * 36 + 2 + wb;
        #pragma unroll
        for (int cc = 0; cc < 4; ++cc)
            dp[cc] = m_[0][cc] * x_[0][cc] + m_[1][cc] * x_[1][cc] + m_[2][cc] * x_[2][cc];
    }
    for (int t = tid; t < 272; t += TPB) {
        int eh, ew; ring_pos(t, eh, ew);
        const int src = ringsrc[t];
        float s = 0.f;
        if (src >= 0) {
            #pragma unroll
            for (int c = 0; c < 3; ++c)
                s += m_ring[c][t] * LD_AG(strip + src + c * 256);
        }
        dext[eh * 36 + ew] = s;
    }
    __syncthreads();
    float csum0 = 0.f;
    {
        const float4 qv = conv_k2(dext, row, wb, h0, w0, K2sh, Ctop, Cbot,
                                  CLf, CLt, CLb, CRf, CRt, CRb);
        const float qa[4] = {qv.x, qv.y, qv.z, qv.w};
        #pragma unroll
        for (int c = 0; c < 3; ++c)
            #pragma unroll
            for (int cc = 0; cc < 4; ++cc) {
                const float b = x_[c][cc];
                const float rv = b - (rho * b + m_[c][cc] * qa[cc]);
                r_[c][cc] = rv; p_[c][cc] = rv;
                csum0 += rv * rv;
            }
    }
    #pragma unroll
    for (int c = 0; c < 3; ++c) {
        if (row < 2) {
            #pragma unroll
            for (int cc = 0; cc < 4; ++cc) sstage[c * 256 + row * 32 + wb + cc] = r_[c][cc];
        }
        if (row >= 30) {
            #pragma unroll
            for (int cc = 0; cc < 4; ++cc) sstage[c * 256 + 64 + (row - 30) * 32 + wb + cc] = r_[c][cc];
        }
        if (wb == 0)  { sstage[c * 256 + 128 + row * 2]     = r_[c][0];
                        sstage[c * 256 + 128 + row * 2 + 1] = r_[c][1]; }
        if (wb == 28) { sstage[c * 256 + 192 + row * 2]     = r_[c][2];
                        sstage[c * 256 + 192 + row * 2 + 1] = r_[c][3]; }
    }
    __syncthreads();
    for (int t = tid; t < STRIP_F; t += TPB)
        ST_AG(strip + STRIPBUF + T * STRIP_F + t, sstage[t]);

    float critj = frb(csum0, rnd++, ctrl, my_xcc, xn, ng);   // r0 strips visible

    for (int t = tid; t < 272; t += TPB) {
        const int src = ringsrc[t];
        if (src >= 0) {
            #pragma unroll
            for (int c = 0; c < 3; ++c)
                p_ring[c][t] = LD_AG(strip + STRIPBUF + src + c * 256);
        }
    }

    // ---- CG loop: 2 frb per iteration
    for (int j = 0; j < NITER; ++j) {
        const bool active = critj >= TOL;

        {
            float* dp = dext + (row + 2) * 36 + 2 + wb;
            #pragma unroll
            for (int cc = 0; cc < 4; ++cc)
                dp[cc] = m_[0][cc] * p_[0][cc] + m_[1][cc] * p_[1][cc] + m_[2][cc] * p_[2][cc];
        }
        for (int t = tid; t < 272; t += TPB) {
            int eh, ew; ring_pos(t, eh, ew);
            float s = 0.f;
            #pragma unroll
            for (int c = 0; c < 3; ++c) s += m_ring[c][t] * p_ring[c][t];
            dext[eh * 36 + ew] = s;
        }
        __syncthreads();
        float dsum = 0.f;
        {
            const float4 qv = conv_k2(dext, row, wb, h0, w0, K2sh, Ctop, Cbot,
                                      CLf, CLt, CLb, CRf, CRt, CRb);
            const float qa[4] = {qv.x, qv.y, qv.z, qv.w};
            #pragma unroll
            for (int c = 0; c < 3; ++c)
                #pragma unroll
                for (int cc = 0; cc < 4; ++cc) {
                    const float ap = rho * p_[c][cc] + m_[c][cc] * qa[cc];
                    Ap_[c][cc] = ap;
                    dsum += p_[c][cc] * ap;
                }
        }
        const float denom = frb(dsum, rnd++, ctrl, my_xcc, xn, ng);

        const float alpha = critj / (active ? denom : 1.0f);
        float csum = 0.f;
        #pragma unroll
        for (int c = 0; c < 3; ++c)
            #pragma unroll
            for (int cc = 0; cc < 4; ++cc) {
                if (active) {
                    x_[c][cc] += alpha * p_[c][cc];
                    r_[c][cc] -= alpha * Ap_[c][cc];
                }
                csum += r_[c][cc] * r_[c][cc];
            }
        #pragma unroll
        for (int c = 0; c < 3; ++c) {
            if (row < 2) {
                #pragma unroll
                for (int cc = 0; cc < 4; ++cc) sstage[c * 256 + row * 32 + wb + cc] = r_[c][cc];
            }
            if (row >= 30) {
                #pragma unroll
                for (int cc = 0; cc < 4; ++cc) sstage[c * 256 + 64 + (row - 30) * 32 + wb + cc] = r_[c][cc];
            }
            if (wb == 0)  { sstage[c * 256 + 128 + row * 2]     = r_[c][0];
                            sstage[c * 256 + 128 + row * 2 + 1] = r_[c][1]; }
            if (wb == 28) { sstage[c * 256 + 192 + row * 2]     = r_[c][2];
                            sstage[c * 256 + 192 + row * 2 + 1] = r_[c][3]; }
        }
        __syncthreads();
        float* gb = strip + (j & 1) * STRIPBUF;
        for (int t = tid; t < STRIP_F; t += TPB)
            ST_AG(gb + T * STRIP_F + t, sstage[t]);

        const float critn = frb(csum, rnd++, ctrl, my_xcc, xn, ng);

        const float beta = critn / (active ? critj : 1.0f);
        if (active) {
            #pragma unroll
            for (int c = 0; c < 3; ++c)
                #pragma unroll
                for (int cc = 0; cc < 4; ++cc)
                    p_[c][cc] = r_[c][cc] + beta * p_[c][cc];
        }
        for (int t = tid; t < 272; t += TPB) {
            const int src = ringsrc[t];
            if (src >= 0) {
                #pragma unroll
                for (int c = 0; c < 3; ++c) {
                    const float rr = LD_AG(gb + src + c * 256);
                    if (active) p_ring[c][t] = rr + beta * p_ring[c][t];
                }
            }
        }
        critj = critn;
    }

    #pragma unroll
    for (int c = 0; c < 3; ++c)
        *(float4*)(x_out + (bi * 3 + c) * HW + roffb) =
            make_float4(x_[c][0], x_[c][1], x_[c][2], x_[c][3]);
}

extern "C" void kernel_launch(void* const* d_in, const int* in_sizes, int n_in,
                              void* d_out, int out_size, void* d_ws, size_t ws_size,
                              hipStream_t stream)
{
    const float* mask = (const float*)d_in[0];
    const float* y    = (const float*)d_in[1];
    const float* z    = (const float*)d_in[2];
    const float* bet  = (const float*)d_in[3];
    const float* rho  = (const float*)d_in[4];
    const float* kern = (const float*)d_in[5];
    float* x  = (float*)d_out;
    float* ws = (float*)d_ws;

    hipMemsetAsync(ws + WS_CTRL, 0, CTRL_F * sizeof(float), stream);

    void* args[] = { (void*)&mask, (void*)&y, (void*)&z, (void*)&bet,
                     (void*)&rho, (void*)&kern, (void*)&x, (void*)&ws };
    hipLaunchCooperativeKernel((void*)cg_persistent, dim3(NBLK), dim3(TPB),
                               args, 0, stream);
}

// Round 9
// 1100.213 us; speedup vs baseline: 5.7452x; 1.1940x over previous
//
#include <hip/hip_runtime.h>

#define TOL 1e-6f
#define NITER 101
#define H 256
#define W 256
#define HW 65536
#define NBLK 256
#define TPB 256

typedef unsigned long long ull;

// ---- workspace layout (float offsets) ----
#define STRIP_F 768                  // floats per block per buffer (3ch x 256)
#define STRIPBUF (NBLK * STRIP_F)
#define WS_CTRL (2 * STRIPBUF)
#define CTRL_F 8192
// ctrl: gvalA[256]@0 gvalB[256]@256 lvalA[8][256]@512 lvalB[8][256]@2560
//       uints @4608: lcnt x*16 | gcnt@128 | icnt@144 | xcnt@160+16x
//       bcastA ull@(u+320) bcastB@(u+448) lbcA@(u+576) lbcB@(u+704)

#define LD_AG(p)    __hip_atomic_load((p), __ATOMIC_RELAXED, __HIP_MEMORY_SCOPE_AGENT)
#define ST_AG(p,v)  __hip_atomic_store((p), (v), __ATOMIC_RELAXED, __HIP_MEMORY_SCOPE_AGENT)

// Opaque identity operands: WITHOUT these, InstCombine rewrites
// atomicrmw add p,0 -> load atomic (same scope); a workgroup-scope atomic
// load is served from the spinner's stale L1 -> infinite spin (the R4/R5
// hang). RMWs execute at >= L2 and can never be L1-stale.
__device__ __forceinline__ unsigned opq0u() {
    unsigned z; asm volatile("s_mov_b32 %0, 0" : "=s"(z)); return z;
}
__device__ __forceinline__ ull opq0ull() {
    return ((ull)opq0u() << 32) | (ull)opq0u();
}
__device__ __forceinline__ float opq0f() { return __uint_as_float(opq0u()); }

// ---------------------------------------------------------------------------
// fused DOUBLE reduce + broadcast + barrier (protocol proven R6-R8).
// ---------------------------------------------------------------------------
__device__ __forceinline__ float2 frb2(float va, float vb, unsigned rnd, float* ctrl,
                                       unsigned my_xcc, unsigned xn, unsigned ng) {
    __shared__ float redA_[4], redB_[4], out_[2];
    asm volatile("s_waitcnt vmcnt(0)" ::: "memory");
    #pragma unroll
    for (int off = 32; off; off >>= 1) {
        va += __shfl_down(va, off, 64);
        vb += __shfl_down(vb, off, 64);
    }
    const int lane = threadIdx.x & 63, wid = threadIdx.x >> 6;
    if (lane == 0) { redA_[wid] = va; redB_[wid] = vb; }
    __syncthreads();
    if (threadIdx.x == 0) {
        const float pa = redA_[0] + redA_[1] + redA_[2] + redA_[3];
        const float pb = redB_[0] + redB_[1] + redB_[2] + redB_[3];
        float* gvalA = ctrl;
        float* gvalB = ctrl + 256;
        float* lvalA = ctrl + 512  + my_xcc * 256;
        float* lvalB = ctrl + 2560 + my_xcc * 256;
        unsigned* cu = (unsigned*)(ctrl + 4608);
        ull* bcastA = (ull*)(cu + 320);
        ull* bcastB = (ull*)(cu + 448);
        ull* lbcA   = (ull*)(cu + 576);
        ull* lbcB   = (ull*)(cu + 704);
        __hip_atomic_fetch_add(lvalA + rnd, pa, __ATOMIC_RELAXED, __HIP_MEMORY_SCOPE_WORKGROUP);
        __hip_atomic_fetch_add(lvalB + rnd, pb, __ATOMIC_RELAXED, __HIP_MEMORY_SCOPE_WORKGROUP);
        asm volatile("s_waitcnt vmcnt(0)" ::: "memory");
        unsigned a = __hip_atomic_fetch_add(cu + my_xcc * 16, 1u,
                         __ATOMIC_RELAXED, __HIP_MEMORY_SCOPE_WORKGROUP);
        ull pkA, pkB;
        if (a == rnd * xn - 1u) {                       // XCD leader (last arriver)
            float la = __hip_atomic_fetch_add(lvalA + rnd, opq0f(),
                           __ATOMIC_RELAXED, __HIP_MEMORY_SCOPE_WORKGROUP);
            float lb = __hip_atomic_fetch_add(lvalB + rnd, opq0f(),
                           __ATOMIC_RELAXED, __HIP_MEMORY_SCOPE_WORKGROUP);
            __hip_atomic_fetch_add(gvalA + rnd, la, __ATOMIC_RELAXED, __HIP_MEMORY_SCOPE_AGENT);
            __hip_atomic_fetch_add(gvalB + rnd, lb, __ATOMIC_RELAXED, __HIP_MEMORY_SCOPE_AGENT);
            asm volatile("s_waitcnt vmcnt(0)" ::: "memory");
            unsigned g = __hip_atomic_fetch_add(cu + 128, 1u,
                             __ATOMIC_RELAXED, __HIP_MEMORY_SCOPE_AGENT);
            if (g == rnd * ng - 1u) {                   // global master
                float ta = __hip_atomic_fetch_add(gvalA + rnd, opq0f(),
                               __ATOMIC_RELAXED, __HIP_MEMORY_SCOPE_AGENT);
                float tb = __hip_atomic_fetch_add(gvalB + rnd, opq0f(),
                               __ATOMIC_RELAXED, __HIP_MEMORY_SCOPE_AGENT);
                pkA = ((ull)rnd << 32) | (ull)__float_as_uint(ta);
                pkB = ((ull)rnd << 32) | (ull)__float_as_uint(tb);
                #pragma unroll
                for (int xx = 0; xx < 8; ++xx)
                    __hip_atomic_store(bcastB + xx * 8, pkB,
                                       __ATOMIC_RELAXED, __HIP_MEMORY_SCOPE_AGENT);
                #pragma unroll
                for (int xx = 0; xx < 8; ++xx)
                    __hip_atomic_store(bcastA + xx * 8, pkA,
                                       __ATOMIC_RELAXED, __HIP_MEMORY_SCOPE_AGENT);
            } else {
                for (;;) {
                    pkA = __hip_atomic_fetch_add(bcastA + my_xcc * 8, opq0ull(),
                              __ATOMIC_RELAXED, __HIP_MEMORY_SCOPE_AGENT);
                    if ((unsigned)(pkA >> 32) >= rnd) break;
                    __builtin_amdgcn_s_sleep(2);
                }
                for (;;) {
                    pkB = __hip_atomic_fetch_add(bcastB + my_xcc * 8, opq0ull(),
                              __ATOMIC_RELAXED, __HIP_MEMORY_SCOPE_AGENT);
                    if ((unsigned)(pkB >> 32) >= rnd) break;
                    __builtin_amdgcn_s_sleep(1);
                }
            }
            __hip_atomic_store(lbcB + my_xcc * 8, pkB,
                               __ATOMIC_RELAXED, __HIP_MEMORY_SCOPE_WORKGROUP);
            __hip_atomic_store(lbcA + my_xcc * 8, pkA,
                               __ATOMIC_RELAXED, __HIP_MEMORY_SCOPE_WORKGROUP);
        } else {
            for (;;) {
                pkA = __hip_atomic_fetch_add(lbcA + my_xcc * 8, opq0ull(),
                          __ATOMIC_RELAXED, __HIP_MEMORY_SCOPE_WORKGROUP);
                if ((unsigned)(pkA >> 32) >= rnd) break;
                __builtin_amdgcn_s_sleep(1);
            }
            for (;;) {
                pkB = __hip_atomic_fetch_add(lbcB + my_xcc * 8, opq0ull(),
                          __ATOMIC_RELAXED, __HIP_MEMORY_SCOPE_WORKGROUP);
                if ((unsigned)(pkB >> 32) >= rnd) break;
                __builtin_amdgcn_s_sleep(1);
            }
        }
        out_[0] = __uint_as_float((unsigned)(pkA & 0xffffffffull));
        out_[1] = __uint_as_float((unsigned)(pkB & 0xffffffffull));
    }
    __syncthreads();
    return make_float2(out_[0], out_[1]);
}

// halo ring (36x36 minus 32x32 core): 272 positions
__device__ __forceinline__ void ring_pos(int t, int& eh, int& ew) {
    if (t < 72)       { eh = t / 36;                 ew = t - (t / 36) * 36; }
    else if (t < 144) { const int u = t - 72;  eh = 34 + u / 36; ew = u - (u / 36) * 36; }
    else              { const int u = t - 144; eh = 2 + (u >> 2);
                        const int c2 = u & 3;  ew = (c2 < 2) ? c2 : c2 + 32; }
}

// ---------------------------------------------------------------------------
// composite PT(P(.)) as 25-tap K2 over dext + border fixups (proven R7).
// ---------------------------------------------------------------------------
__device__ __forceinline__ float4 conv_k2(const float* dext, int row, int wb,
                                          int h0, int w0,
                                          const float* K2sh,
                                          const float* Ctop, const float* Cbot,
                                          const float* CLf, const float* CLt, const float* CLb,
                                          const float* CRf, const float* CRt, const float* CRb)
{
    float q[4] = {0.f, 0.f, 0.f, 0.f};
    float w2s[8], cL[5], cR[5];
    const float* base = dext + row * 36 + wb;
    #pragma unroll
    for (int A = 0; A < 5; ++A) {
        const float4 lo = *(const float4*)(base + A * 36);
        const float4 hi = *(const float4*)(base + A * 36 + 4);
        const float w8[8] = {lo.x, lo.y, lo.z, lo.w, hi.x, hi.y, hi.z, hi.w};
        #pragma unroll
        for (int cc = 0; cc < 4; ++cc) {
            float s = q[cc];
            #pragma unroll
            for (int Bq = 0; Bq < 5; ++Bq)
                s += K2sh[A * 5 + Bq] * w8[cc + Bq];
            q[cc] = s;
        }
        if (A == 2) {
            #pragma unroll
            for (int u = 0; u < 8; ++u) w2s[u] = w8[u];
        }
        cL[A] = w8[2]; cR[A] = w8[5];
    }
    const int gh = h0 + row, gwb = w0 + wb;
    if (gh == 0) {
        #pragma unroll
        for (int cc = 0; cc < 4; ++cc)
            #pragma unroll
            for (int Bq = 0; Bq < 5; ++Bq)
                q[cc] -= Ctop[Bq] * w2s[cc + Bq];
    }
    if (gh == 255) {
        #pragma unroll
        for (int cc = 0; cc < 4; ++cc)
            #pragma unroll
            for (int Bq = 0; Bq < 5; ++Bq)
                q[cc] -= Cbot[Bq] * w2s[cc + Bq];
    }
    if (gwb == 0) {
        const float* C = (gh == 0) ? CLt : ((gh == 255) ? CLb : CLf);
        #pragma unroll
        for (int A = 0; A < 5; ++A) q[0] -= C[A] * cL[A];
    }
    if (gwb == 252) {
        const float* C = (gh == 0) ? CRt : ((gh == 255) ? CRb : CRf);
        #pragma unroll
        for (int A = 0; A < 5; ++A) q[3] -= C[A] * cR[A];
    }
    return make_float4(q[0], q[1], q[2], q[3]);
}

extern "C" __global__ void __launch_bounds__(TPB)
cg_persistent(const float* __restrict__ mask, const float* __restrict__ y,
              const float* __restrict__ z, const float* __restrict__ bet,
              const float* __restrict__ rho_p, const float* __restrict__ kern,
              float* __restrict__ x_out, float* __restrict__ ws)
{
    __shared__ float ksh[27];
    __shared__ __align__(16) float dext[36 * 36];
    __shared__ float m_ring[3][272];
    __shared__ float r_ring[3][272];
    __shared__ float q_ring[3][272];
    __shared__ float sstage[STRIP_F];
    __shared__ int   ringsrc[272];
    __shared__ float K2sh[25];
    __shared__ float Ctop[5], Cbot[5];
    __shared__ float CLf[5], CLt[5], CLb[5], CRf[5], CRt[5], CRb[5];

    float* strip = ws;
    float* ctrl  = ws + WS_CTRL;

    const int tid = threadIdx.x;
    const int T  = blockIdx.x;
    const int bi = T >> 6;
    const int h0 = ((T >> 3) & 7) << 5;
    const int w0 = (T & 7) << 5;
    const int row = tid >> 3;
    const int wb  = (tid & 7) << 2;
    const int roffb = (h0 + row) * W + (w0 + wb);

    unsigned xcc_raw;
    asm volatile("s_getreg_b32 %0, hwreg(HW_REG_XCC_ID)" : "=s"(xcc_raw));
    const unsigned my_xcc = xcc_raw & 7u;

    unsigned xn = 0, ng = 0;
    unsigned* cu = (unsigned*)(ctrl + 4608);
    if (tid == 0) {
        __hip_atomic_fetch_add(cu + 160 + 16 * my_xcc, 1u,
                               __ATOMIC_RELAXED, __HIP_MEMORY_SCOPE_AGENT);
        __hip_atomic_fetch_add(cu + 144, 1u,
                               __ATOMIC_RELAXED, __HIP_MEMORY_SCOPE_AGENT);
    }

    if (tid < 27) ksh[tid] = kern[tid];
    const float rho = rho_p[0];

    float m_[3][4], x_[3][4], r_[3][4], p_[3][4], q_[3][4], w_[3][4];
    #pragma unroll
    for (int c = 0; c < 3; ++c) {
        const float4 mv = *(const float4*)(mask + (bi * 3 + c) * HW + roffb);
        m_[c][0] = mv.x; m_[c][1] = mv.y; m_[c][2] = mv.z; m_[c][3] = mv.w;
    }

    // m_ring + iteration-invariant ring -> neighbor-strip index table
    for (int t = tid; t < 272; t += TPB) {
        int eh, ew; ring_pos(t, eh, ew);
        const int gh = h0 + eh - 2, gw = w0 + ew - 2;
        const bool valid = (unsigned)gh < (unsigned)H && (unsigned)gw < (unsigned)W;
        int src = -1;
        if (valid) {
            const int tr = gh >> 5, tc = gw >> 5;
            const int Tn = (bi << 6) | (tr << 3) | tc;
            const int lh = gh & 31, lw = gw & 31;
            int idx;
            if (tr != (h0 >> 5)) idx = (lh >= 30) ? 64 + (lh - 30) * 32 + lw : lh * 32 + lw;
            else                 idx = (lw >= 30) ? 192 + lh * 2 + (lw - 30) : 128 + lh * 2 + lw;
            src = Tn * STRIP_F + idx;
        }
        ringsrc[t] = src;
        #pragma unroll
        for (int c = 0; c < 3; ++c) {
            m_ring[c][t] = valid ? mask[(bi * 3 + c) * HW + gh * W + gw] : 0.f;
            r_ring[c][t] = 0.f;
            q_ring[c][t] = 0.f;
        }
    }

    // ---- I-a: fill dext from y
    for (int e = tid; e < 1296; e += TPB) {
        const int eh = e / 36, ew = e - eh * 36;
        const int gh = h0 + eh - 2, gw = w0 + ew - 2;
        dext[e] = ((unsigned)gh < (unsigned)H && (unsigned)gw < (unsigned)W)
                      ? y[bi * HW + gh * W + gw] : 0.f;
    }
    __syncthreads();

    // ---- composite tables
    if (tid < 25) {
        const int A = tid / 5, Bq = tid % 5;
        float s = 0.f;
        for (int o = 0; o < 3; ++o)
            for (int i = (A > 2 ? A - 2 : 0); i <= (A < 2 ? A : 2); ++i)
                for (int j = (Bq > 2 ? Bq - 2 : 0); j <= (Bq < 2 ? Bq : 2); ++j)
                    s += ksh[o * 9 + (A - i) * 3 + (Bq - j)] * ksh[o * 9 + (2 - i) * 3 + (2 - j)];
        K2sh[tid] = s;
    } else if (tid < 35) {
        const int Bq = (tid - 25) % 5;
        const int krow = (tid < 30) ? 6 : 0;
        float s = 0.f;
        for (int o = 0; o < 3; ++o)
            for (int j = (Bq > 2 ? Bq - 2 : 0); j <= (Bq < 2 ? Bq : 2); ++j)
                s += ksh[o * 9 + krow + (Bq - j)] * ksh[o * 9 + krow + (2 - j)];
        if (tid < 30) Ctop[Bq] = s; else Cbot[Bq] = s;
    } else if (tid < 65) {
        const int u = tid - 35;
        const int side = u / 15;
        const int v = (u % 15) / 5;
        const int A = u % 5;
        const int kcol = side ? 0 : 2;
        int ilo = (A > 2 ? A - 2 : 0), ihi = (A < 2 ? A : 2);
        if (v == 1 && ilo < 1) ilo = 1;
        if (v == 2 && ihi > 1) ihi = 1;
        float s = 0.f;
        for (int o = 0; o < 3; ++o)
            for (int i = ilo; i <= ihi; ++i)
                s += ksh[o * 9 + (A - i) * 3 + kcol] * ksh[o * 9 + (2 - i) * 3 + kcol];
        float* dst = side ? (v == 0 ? CRf : v == 1 ? CRt : CRb)
                          : (v == 0 ? CLf : v == 1 ? CLt : CLb);
        dst[A] = s;
    }
    __syncthreads();

    // helper lambda-ish macro: stage a [3][4] register array's border to sstage
#define STAGE_BORDER(SRC)                                                          \
    _Pragma("unroll")                                                              \
    for (int c = 0; c < 3; ++c) {                                                  \
        if (row < 2) {                                                             \
            _Pragma("unroll")                                                      \
            for (int cc = 0; cc < 4; ++cc)                                         \
                sstage[c * 256 + row * 32 + wb + cc] = SRC[c][cc];                 \
        }                                                                          \
        if (row >= 30) {                                                           \
            _Pragma("unroll")                                                      \
            for (int cc = 0; cc < 4; ++cc)                                         \
                sstage[c * 256 + 64 + (row - 30) * 32 + wb + cc] = SRC[c][cc];     \
        }                                                                          \
        if (wb == 0)  { sstage[c * 256 + 128 + row * 2]     = SRC[c][0];           \
                        sstage[c * 256 + 128 + row * 2 + 1] = SRC[c][1]; }         \
        if (wb == 28) { sstage[c * 256 + 192 + row * 2]     = SRC[c][2];           \
                        sstage[c * 256 + 192 + row * 2 + 1] = SRC[c][3]; }         \
    }

    // I-a: q0conv = PT(P(y)); b = m*q0conv + rho*(z-bet); x = b; publish b -> buf0
    {
        const float4 qv = conv_k2(dext, row, wb, h0, w0, K2sh, Ctop, Cbot,
                                  CLf, CLt, CLb, CRf, CRt, CRb);
        const float qa[4] = {qv.x, qv.y, qv.z, qv.w};
        #pragma unroll
        for (int c = 0; c < 3; ++c) {
            const int gi = (bi * 3 + c) * HW + roffb;
            const float4 zv = *(const float4*)(z + gi);
            const float4 bv = *(const float4*)(bet + gi);
            const float zz[4] = {zv.x, zv.y, zv.z, zv.w};
            const float bb[4] = {bv.x, bv.y, bv.z, bv.w};
            #pragma unroll
            for (int cc = 0; cc < 4; ++cc)
                x_[c][cc] = m_[c][cc] * qa[cc] + rho * (zz[cc] - bb[cc]);
        }
    }
    STAGE_BORDER(x_)
    __syncthreads();
    for (int t = tid; t < STRIP_F; t += TPB)
        ST_AG(strip + T * STRIP_F + t, sstage[t]);

    // finish population count -> xn, ng (opaque RMW polls)
    if (tid == 0) {
        while (__hip_atomic_fetch_add(cu + 144, opq0u(), __ATOMIC_RELAXED,
                                      __HIP_MEMORY_SCOPE_AGENT) < (unsigned)NBLK)
            __builtin_amdgcn_s_sleep(32);
        ng = 0;
        #pragma unroll
        for (int i = 0; i < 8; ++i) {
            unsigned c = __hip_atomic_fetch_add(cu + 160 + 16 * i, opq0u(),
                             __ATOMIC_RELAXED, __HIP_MEMORY_SCOPE_AGENT);
            ng += (c > 0u);
        }
        xn = __hip_atomic_fetch_add(cu + 160 + 16 * my_xcc, opq0u(),
                 __ATOMIC_RELAXED, __HIP_MEMORY_SCOPE_AGENT);
    }
    unsigned rnd = 1;
    frb2(0.f, 0.f, rnd++, ctrl, my_xcc, xn, ng);     // b strips visible

    // ---- I-b: d0 = sum m*b; r0 = b - A(b); gamma0; publish r0 -> buf1
    {
        float* dp = dext + (row + 2) * 36 + 2 + wb;
        #pragma unroll
        for (int cc = 0; cc < 4; ++cc)
            dp[cc] = m_[0][cc] * x_[0][cc] + m_[1][cc] * x_[1][cc] + m_[2][cc] * x_[2][cc];
    }
    for (int t = tid; t < 272; t += TPB) {
        int eh, ew; ring_pos(t, eh, ew);
        const int src = ringsrc[t];
        float s = 0.f;
        if (src >= 0) {
            #pragma unroll
            for (int c = 0; c < 3; ++c)
                s += m_ring[c][t] * LD_AG(strip + src + c * 256);
        }
        dext[eh * 36 + ew] = s;
    }
    __syncthreads();
    float gsum0 = 0.f;
    {
        const float4 qv = conv_k2(dext, row, wb, h0, w0, K2sh, Ctop, Cbot,
                                  CLf, CLt, CLb, CRf, CRt, CRb);
        const float qa[4] = {qv.x, qv.y, qv.z, qv.w};
        #pragma unroll
        for (int c = 0; c < 3; ++c)
            #pragma unroll
            for (int cc = 0; cc < 4; ++cc) {
                const float b = x_[c][cc];
                const float rv = b - (rho * b + m_[c][cc] * qa[cc]);
                r_[c][cc] = rv; p_[c][cc] = rv;
                gsum0 += rv * rv;
            }
    }
    STAGE_BORDER(r_)
    __syncthreads();
    for (int t = tid; t < STRIP_F; t += TPB)
        ST_AG(strip + STRIPBUF + T * STRIP_F + t, sstage[t]);

    float gamma = frb2(gsum0, 0.f, rnd++, ctrl, my_xcc, xn, ng).x;  // r0 visible

    // r_ring <- r0 halo
    for (int t = tid; t < 272; t += TPB) {
        const int src = ringsrc[t];
        if (src >= 0) {
            #pragma unroll
            for (int c = 0; c < 3; ++c)
                r_ring[c][t] = LD_AG(strip + STRIPBUF + src + c * 256);
        }
    }

    // ---- I-c: w0 = A(r0); delta0 = r0.w0; q = w0; publish w0 -> buf0
    {
        float* dp = dext + (row + 2) * 36 + 2 + wb;
        #pragma unroll
        for (int cc = 0; cc < 4; ++cc)
            dp[cc] = m_[0][cc] * r_[0][cc] + m_[1][cc] * r_[1][cc] + m_[2][cc] * r_[2][cc];
    }
    for (int t = tid; t < 272; t += TPB) {
        int eh, ew; ring_pos(t, eh, ew);
        float s = 0.f;
        #pragma unroll
        for (int c = 0; c < 3; ++c) s += m_ring[c][t] * r_ring[c][t];
        dext[eh * 36 + ew] = s;
    }
    __syncthreads();
    float dsum0 = 0.f;
    {
        const float4 qv = conv_k2(dext, row, wb, h0, w0, K2sh, Ctop, Cbot,
                                  CLf, CLt, CLb, CRf, CRt, CRb);
        const float qa[4] = {qv.x, qv.y, qv.z, qv.w};
        #pragma unroll
        for (int c = 0; c < 3; ++c)
            #pragma unroll
            for (int cc = 0; cc < 4; ++cc) {
                const float wv = rho * r_[c][cc] + m_[c][cc] * qa[cc];
                q_[c][cc] = wv;
                dsum0 += r_[c][cc] * wv;
            }
    }
    STAGE_BORDER(q_)
    __syncthreads();
    for (int t = tid; t < STRIP_F; t += TPB)
        ST_AG(strip + T * STRIP_F + t, sstage[t]);

    const float delta0 = frb2(dsum0, 0.f, rnd++, ctrl, my_xcc, xn, ng).x; // w0 vis

    // q_ring <- w0 halo
    for (int t = tid; t < 272; t += TPB) {
        const int src = ringsrc[t];
        if (src >= 0) {
            #pragma unroll
            for (int c = 0; c < 3; ++c)
                q_ring[c][t] = LD_AG(strip + src + c * 256);
        }
    }
    float alpha = (gamma >= TOL) ? (gamma / delta0) : 0.f;

    // ---- CG loop: ONE frb2 per iteration (Chronopoulos-Gear CG).
    // beta = gamma'/gamma (both MEASURED -> no recurrence feedback, the R8
    // failure mode); alpha' = gamma'/(delta' - beta*gamma'/alpha) equals
    // gamma'/(p'.Ap') in exact arithmetic.
    for (int j = 0; j < NITER; ++j) {
        const bool active = (gamma >= TOL);

        if (active) {
            #pragma unroll
            for (int c = 0; c < 3; ++c)
                #pragma unroll
                for (int cc = 0; cc < 4; ++cc) {
                    x_[c][cc] += alpha * p_[c][cc];
                    r_[c][cc] -= alpha * q_[c][cc];
                }
            for (int t = tid; t < 272; t += TPB) {
                #pragma unroll
                for (int c = 0; c < 3; ++c)
                    r_ring[c][t] -= alpha * q_ring[c][t];
            }
        }

        // w = A(r): d = sum m*r (core + ring)
        {
            float* dp = dext + (row + 2) * 36 + 2 + wb;
            #pragma unroll
            for (int cc = 0; cc < 4; ++cc)
                dp[cc] = m_[0][cc] * r_[0][cc] + m_[1][cc] * r_[1][cc] + m_[2][cc] * r_[2][cc];
        }
        for (int t = tid; t < 272; t += TPB) {
            int eh, ew; ring_pos(t, eh, ew);
            float s = 0.f;
            #pragma unroll
            for (int c = 0; c < 3; ++c) s += m_ring[c][t] * r_ring[c][t];
            dext[eh * 36 + ew] = s;
        }
        __syncthreads();
        float gsum = 0.f, dsum = 0.f;
        {
            const float4 qv = conv_k2(dext, row, wb, h0, w0, K2sh, Ctop, Cbot,
                                      CLf, CLt, CLb, CRf, CRt, CRb);
            const float qa[4] = {qv.x, qv.y, qv.z, qv.w};
            #pragma unroll
            for (int c = 0; c < 3; ++c)
                #pragma unroll
                for (int cc = 0; cc < 4; ++cc) {
                    const float rv = r_[c][cc];
                    const float wv = rho * rv + m_[c][cc] * qa[cc];
                    w_[c][cc] = wv;
                    gsum += rv * rv;
                    dsum += rv * wv;
                }
        }
        // publish w strips (pre-frb; frb is the separating barrier).
        // parity (j+1)&1: j=0 -> buf1 (audited vs init-publish read windows).
        STAGE_BORDER(w_)
        __syncthreads();
        float* gb = strip + ((j + 1) & 1) * STRIPBUF;
        for (int t = tid; t < STRIP_F; t += TPB)
            ST_AG(gb + T * STRIP_F + t, sstage[t]);

        const float2 gd = frb2(gsum, dsum, rnd++, ctrl, my_xcc, xn, ng);

        if (active) {
            const float gp = gd.x, dp = gd.y;
            const float beta = gp / gamma;
            const float alphan = gp / (dp - beta * gp / alpha);
            #pragma unroll
            for (int c = 0; c < 3; ++c)
                #pragma unroll
                for (int cc = 0; cc < 4; ++cc) {
                    p_[c][cc] = r_[c][cc] + beta * p_[c][cc];
                    q_[c][cc] = w_[c][cc] + beta * q_[c][cc];
                }
            for (int t = tid; t < 272; t += TPB) {
                const int src = ringsrc[t];
                if (src >= 0) {
                    #pragma unroll
                    for (int c = 0; c < 3; ++c) {
                        const float wn = LD_AG(gb + src + c * 256);
                        q_ring[c][t] = wn + beta * q_ring[c][t];
                    }
                }
            }
            gamma = gp;
            alpha = alphan;
        }
    }

    #pragma unroll
    for (int c = 0; c < 3; ++c)
        *(float4*)(x_out + (bi * 3 + c) * HW + roffb) =
            make_float4(x_[c][0], x_[c][1], x_[c][2], x_[c][3]);
}

extern "C" void kernel_launch(void* const* d_in, const int* in_sizes, int n_in,
                              void* d_out, int out_size, void* d_ws, size_t ws_size,
                              hipStream_t stream)
{
    const float* mask = (const float*)d_in[0];
    const float* y    = (const float*)d_in[1];
    const float* z    = (const float*)d_in[2];
    const float* bet  = (const float*)d_in[3];
    const float* rho  = (const float*)d_in[4];
    const float* kern = (const float*)d_in[5];
    float* x  = (float*)d_out;
    float* ws = (float*)d_ws;

    hipMemsetAsync(ws + WS_CTRL, 0, CTRL_F * sizeof(float), stream);

    void* args[] = { (void*)&mask, (void*)&y, (void*)&z, (void*)&bet,
                     (void*)&rho, (void*)&kern, (void*)&x, (void*)&ws };
    hipLaunchCooperativeKernel((void*)cg_persistent, dim3(NBLK), dim3(TPB),
                               args, 0, stream);
}

// Round 10
// 1070.458 us; speedup vs baseline: 5.9049x; 1.0278x over previous
//
#include <hip/hip_runtime.h>

#define TOL 1e-6f
#define NITER 101
#define H 256
#define W 256
#define HW 65536
#define NBLK 256
#define TPB 256

typedef unsigned long long ull;

// ---- workspace layout (float offsets) ----
#define STRIP_F 768                  // floats per block per buffer (3ch x 256)
#define STRIPBUF (NBLK * STRIP_F)
#define WS_CTRL (2 * STRIPBUF)
#define CTRL_F 8192
// ctrl: gvalA[256]@0 gvalB[256]@256 lvalA[8][256]@512 lvalB[8][256]@2560
//       uints @4608: lcnt x*16 | gcnt@128 | icnt@144 | xcnt@160+16x
//       bcastA ull@(u+320)+x*8   bcastB ull@(u+448)+x*8       (leader-polled)
//       lbcA  ull@(u+576)+(x*4+s)*8   (32 lines, 4 sub-lines/XCD)
//       lbcB  ull@(u+1088)+(x*4+s)*8  (32 lines)

#define LD_AG(p)    __hip_atomic_load((p), __ATOMIC_RELAXED, __HIP_MEMORY_SCOPE_AGENT)
#define ST_AG(p,v)  __hip_atomic_store((p), (v), __ATOMIC_RELAXED, __HIP_MEMORY_SCOPE_AGENT)

// Opaque identity operands: WITHOUT these, InstCombine rewrites
// atomicrmw add p,0 -> load atomic (same scope); a workgroup-scope atomic
// load is served from the spinner's stale L1 -> infinite spin (the R4/R5
// hang). RMWs execute at >= L2 and can never be L1-stale.
__device__ __forceinline__ unsigned opq0u() {
    unsigned z; asm volatile("s_mov_b32 %0, 0" : "=s"(z)); return z;
}
__device__ __forceinline__ ull opq0ull() {
    return ((ull)opq0u() << 32) | (ull)opq0u();
}
__device__ __forceinline__ float opq0f() { return __uint_as_float(opq0u()); }

// ---------------------------------------------------------------------------
// fused DOUBLE reduce + broadcast + barrier.
// R10: release fan-out split 4-way per XCD (spinner line load 31 -> ~8
// pollers: leader's release store stops queueing behind poll saturation,
// exit-RMW serialization 4x shorter); leader's private bcast poll sleepless.
// ---------------------------------------------------------------------------
__device__ __forceinline__ float2 frb2(float va, float vb, unsigned rnd, float* ctrl,
                                       unsigned my_xcc, unsigned xn, unsigned ng) {
    __shared__ float redA_[4], redB_[4], out_[2];
    asm volatile("s_waitcnt vmcnt(0)" ::: "memory");
    #pragma unroll
    for (int off = 32; off; off >>= 1) {
        va += __shfl_down(va, off, 64);
        vb += __shfl_down(vb, off, 64);
    }
    const int lane = threadIdx.x & 63, wid = threadIdx.x >> 6;
    if (lane == 0) { redA_[wid] = va; redB_[wid] = vb; }
    __syncthreads();
    if (threadIdx.x == 0) {
        const float pa = redA_[0] + redA_[1] + redA_[2] + redA_[3];
        const float pb = redB_[0] + redB_[1] + redB_[2] + redB_[3];
        const unsigned sub = (blockIdx.x >> 3) & 3u;   // spinner sub-line
        float* gvalA = ctrl;
        float* gvalB = ctrl + 256;
        float* lvalA = ctrl + 512  + my_xcc * 256;
        float* lvalB = ctrl + 2560 + my_xcc * 256;
        unsigned* cu = (unsigned*)(ctrl + 4608);
        ull* bcastA = (ull*)(cu + 320);
        ull* bcastB = (ull*)(cu + 448);
        ull* lbcA   = (ull*)(cu + 576);
        ull* lbcB   = (ull*)(cu + 1088);
        __hip_atomic_fetch_add(lvalA + rnd, pa, __ATOMIC_RELAXED, __HIP_MEMORY_SCOPE_WORKGROUP);
        __hip_atomic_fetch_add(lvalB + rnd, pb, __ATOMIC_RELAXED, __HIP_MEMORY_SCOPE_WORKGROUP);
        asm volatile("s_waitcnt vmcnt(0)" ::: "memory");
        unsigned a = __hip_atomic_fetch_add(cu + my_xcc * 16, 1u,
                         __ATOMIC_RELAXED, __HIP_MEMORY_SCOPE_WORKGROUP);
        ull pkA, pkB;
        if (a == rnd * xn - 1u) {                       // XCD leader (last arriver)
            float la = __hip_atomic_fetch_add(lvalA + rnd, opq0f(),
                           __ATOMIC_RELAXED, __HIP_MEMORY_SCOPE_WORKGROUP);
            float lb = __hip_atomic_fetch_add(lvalB + rnd, opq0f(),
                           __ATOMIC_RELAXED, __HIP_MEMORY_SCOPE_WORKGROUP);
            __hip_atomic_fetch_add(gvalA + rnd, la, __ATOMIC_RELAXED, __HIP_MEMORY_SCOPE_AGENT);
            __hip_atomic_fetch_add(gvalB + rnd, lb, __ATOMIC_RELAXED, __HIP_MEMORY_SCOPE_AGENT);
            asm volatile("s_waitcnt vmcnt(0)" ::: "memory");
            unsigned g = __hip_atomic_fetch_add(cu + 128, 1u,
                             __ATOMIC_RELAXED, __HIP_MEMORY_SCOPE_AGENT);
            if (g == rnd * ng - 1u) {                   // global master
                float ta = __hip_atomic_fetch_add(gvalA + rnd, opq0f(),
                               __ATOMIC_RELAXED, __HIP_MEMORY_SCOPE_AGENT);
                float tb = __hip_atomic_fetch_add(gvalB + rnd, opq0f(),
                               __ATOMIC_RELAXED, __HIP_MEMORY_SCOPE_AGENT);
                pkA = ((ull)rnd << 32) | (ull)__float_as_uint(ta);
                pkB = ((ull)rnd << 32) | (ull)__float_as_uint(tb);
                #pragma unroll
                for (int xx = 0; xx < 8; ++xx)
                    __hip_atomic_store(bcastB + xx * 8, pkB,
                                       __ATOMIC_RELAXED, __HIP_MEMORY_SCOPE_AGENT);
                #pragma unroll
                for (int xx = 0; xx < 8; ++xx)
                    __hip_atomic_store(bcastA + xx * 8, pkA,
                                       __ATOMIC_RELAXED, __HIP_MEMORY_SCOPE_AGENT);
            } else {
                // private line (one poller) -> sleepless tight poll
                for (;;) {
                    pkA = __hip_atomic_fetch_add(bcastA + my_xcc * 8, opq0ull(),
                              __ATOMIC_RELAXED, __HIP_MEMORY_SCOPE_AGENT);
                    if ((unsigned)(pkA >> 32) >= rnd) break;
                }
                for (;;) {
                    pkB = __hip_atomic_fetch_add(bcastB + my_xcc * 8, opq0ull(),
                              __ATOMIC_RELAXED, __HIP_MEMORY_SCOPE_AGENT);
                    if ((unsigned)(pkB >> 32) >= rnd) break;
                }
            }
            // fan out to 4 sub-lines per channel (B first, then A)
            #pragma unroll
            for (int s = 0; s < 4; ++s)
                __hip_atomic_store(lbcB + (my_xcc * 4 + s) * 8, pkB,
                                   __ATOMIC_RELAXED, __HIP_MEMORY_SCOPE_WORKGROUP);
            #pragma unroll
            for (int s = 0; s < 4; ++s)
                __hip_atomic_store(lbcA + (my_xcc * 4 + s) * 8, pkA,
                                   __ATOMIC_RELAXED, __HIP_MEMORY_SCOPE_WORKGROUP);
        } else {
            ull* mylA = lbcA + (my_xcc * 4 + sub) * 8;
            ull* mylB = lbcB + (my_xcc * 4 + sub) * 8;
            for (;;) {
                pkA = __hip_atomic_fetch_add(mylA, opq0ull(),
                          __ATOMIC_RELAXED, __HIP_MEMORY_SCOPE_WORKGROUP);
                if ((unsigned)(pkA >> 32) >= rnd) break;
                __builtin_amdgcn_s_sleep(2);
            }
            for (;;) {
                pkB = __hip_atomic_fetch_add(mylB, opq0ull(),
                          __ATOMIC_RELAXED, __HIP_MEMORY_SCOPE_WORKGROUP);
                if ((unsigned)(pkB >> 32) >= rnd) break;
                __builtin_amdgcn_s_sleep(1);
            }
        }
        out_[0] = __uint_as_float((unsigned)(pkA & 0xffffffffull));
        out_[1] = __uint_as_float((unsigned)(pkB & 0xffffffffull));
    }
    __syncthreads();
    return make_float2(out_[0], out_[1]);
}

// halo ring (36x36 minus 32x32 core): 272 positions
__device__ __forceinline__ void ring_pos(int t, int& eh, int& ew) {
    if (t < 72)       { eh = t / 36;                 ew = t - (t / 36) * 36; }
    else if (t < 144) { const int u = t - 72;  eh = 34 + u / 36; ew = u - (u / 36) * 36; }
    else              { const int u = t - 144; eh = 2 + (u >> 2);
                        const int c2 = u & 3;  ew = (c2 < 2) ? c2 : c2 + 32; }
}

// ---------------------------------------------------------------------------
// composite PT(P(.)) as 25-tap K2 over dext + border fixups (proven R7).
// ---------------------------------------------------------------------------
__device__ __forceinline__ float4 conv_k2(const float* dext, int row, int wb,
                                          int h0, int w0,
                                          const float* K2sh,
                                          const float* Ctop, const float* Cbot,
                                          const float* CLf, const float* CLt, const float* CLb,
                                          const float* CRf, const float* CRt, const float* CRb)
{
    float q[4] = {0.f, 0.f, 0.f, 0.f};
    float w2s[8], cL[5], cR[5];
    const float* base = dext + row * 36 + wb;
    #pragma unroll
    for (int A = 0; A < 5; ++A) {
        const float4 lo = *(const float4*)(base + A * 36);
        const float4 hi = *(const float4*)(base + A * 36 + 4);
        const float w8[8] = {lo.x, lo.y, lo.z, lo.w, hi.x, hi.y, hi.z, hi.w};
        #pragma unroll
        for (int cc = 0; cc < 4; ++cc) {
            float s = q[cc];
            #pragma unroll
            for (int Bq = 0; Bq < 5; ++Bq)
                s += K2sh[A * 5 + Bq] * w8[cc + Bq];
            q[cc] = s;
        }
        if (A == 2) {
            #pragma unroll
            for (int u = 0; u < 8; ++u) w2s[u] = w8[u];
        }
        cL[A] = w8[2]; cR[A] = w8[5];
    }
    const int gh = h0 + row, gwb = w0 + wb;
    if (gh == 0) {
        #pragma unroll
        for (int cc = 0; cc < 4; ++cc)
            #pragma unroll
            for (int Bq = 0; Bq < 5; ++Bq)
                q[cc] -= Ctop[Bq] * w2s[cc + Bq];
    }
    if (gh == 255) {
        #pragma unroll
        for (int cc = 0; cc < 4; ++cc)
            #pragma unroll
            for (int Bq = 0; Bq < 5; ++Bq)
                q[cc] -= Cbot[Bq] * w2s[cc + Bq];
    }
    if (gwb == 0) {
        const float* C = (gh == 0) ? CLt : ((gh == 255) ? CLb : CLf);
        #pragma unroll
        for (int A = 0; A < 5; ++A) q[0] -= C[A] * cL[A];
    }
    if (gwb == 252) {
        const float* C = (gh == 0) ? CRt : ((gh == 255) ? CRb : CRf);
        #pragma unroll
        for (int A = 0; A < 5; ++A) q[3] -= C[A] * cR[A];
    }
    return make_float4(q[0], q[1], q[2], q[3]);
}

extern "C" __global__ void __launch_bounds__(TPB)
cg_persistent(const float* __restrict__ mask, const float* __restrict__ y,
              const float* __restrict__ z, const float* __restrict__ bet,
              const float* __restrict__ rho_p, const float* __restrict__ kern,
              float* __restrict__ x_out, float* __restrict__ ws)
{
    __shared__ float ksh[27];
    __shared__ __align__(16) float dext[36 * 36];
    __shared__ float m_ring[3][272];
    __shared__ float r_ring[3][272];
    __shared__ float q_ring[3][272];
    __shared__ float sstage[STRIP_F];
    __shared__ int   ringsrc[272];
    __shared__ float K2sh[25];
    __shared__ float Ctop[5], Cbot[5];
    __shared__ float CLf[5], CLt[5], CLb[5], CRf[5], CRt[5], CRb[5];

    float* strip = ws;
    float* ctrl  = ws + WS_CTRL;

    const int tid = threadIdx.x;
    const int T  = blockIdx.x;
    const int bi = T >> 6;
    const int h0 = ((T >> 3) & 7) << 5;
    const int w0 = (T & 7) << 5;
    const int row = tid >> 3;
    const int wb  = (tid & 7) << 2;
    const int roffb = (h0 + row) * W + (w0 + wb);

    unsigned xcc_raw;
    asm volatile("s_getreg_b32 %0, hwreg(HW_REG_XCC_ID)" : "=s"(xcc_raw));
    const unsigned my_xcc = xcc_raw & 7u;

    unsigned xn = 0, ng = 0;
    unsigned* cu = (unsigned*)(ctrl + 4608);
    if (tid == 0) {
        __hip_atomic_fetch_add(cu + 160 + 16 * my_xcc, 1u,
                               __ATOMIC_RELAXED, __HIP_MEMORY_SCOPE_AGENT);
        __hip_atomic_fetch_add(cu + 144, 1u,
                               __ATOMIC_RELAXED, __HIP_MEMORY_SCOPE_AGENT);
    }

    if (tid < 27) ksh[tid] = kern[tid];
    const float rho = rho_p[0];

    float m_[3][4], x_[3][4], r_[3][4], p_[3][4], q_[3][4], w_[3][4];
    #pragma unroll
    for (int c = 0; c < 3; ++c) {
        const float4 mv = *(const float4*)(mask + (bi * 3 + c) * HW + roffb);
        m_[c][0] = mv.x; m_[c][1] = mv.y; m_[c][2] = mv.z; m_[c][3] = mv.w;
    }

    // m_ring + iteration-invariant ring -> neighbor-strip index table
    for (int t = tid; t < 272; t += TPB) {
        int eh, ew; ring_pos(t, eh, ew);
        const int gh = h0 + eh - 2, gw = w0 + ew - 2;
        const bool valid = (unsigned)gh < (unsigned)H && (unsigned)gw < (unsigned)W;
        int src = -1;
        if (valid) {
            const int tr = gh >> 5, tc = gw >> 5;
            const int Tn = (bi << 6) | (tr << 3) | tc;
            const int lh = gh & 31, lw = gw & 31;
            int idx;
            if (tr != (h0 >> 5)) idx = (lh >= 30) ? 64 + (lh - 30) * 32 + lw : lh * 32 + lw;
            else                 idx = (lw >= 30) ? 192 + lh * 2 + (lw - 30) : 128 + lh * 2 + lw;
            src = Tn * STRIP_F + idx;
        }
        ringsrc[t] = src;
        #pragma unroll
        for (int c = 0; c < 3; ++c) {
            m_ring[c][t] = valid ? mask[(bi * 3 + c) * HW + gh * W + gw] : 0.f;
            r_ring[c][t] = 0.f;
            q_ring[c][t] = 0.f;
        }
    }

    // ---- I-a: fill dext from y
    for (int e = tid; e < 1296; e += TPB) {
        const int eh = e / 36, ew = e - eh * 36;
        const int gh = h0 + eh - 2, gw = w0 + ew - 2;
        dext[e] = ((unsigned)gh < (unsigned)H && (unsigned)gw < (unsigned)W)
                      ? y[bi * HW + gh * W + gw] : 0.f;
    }
    __syncthreads();

    // ---- composite tables
    if (tid < 25) {
        const int A = tid / 5, Bq = tid % 5;
        float s = 0.f;
        for (int o = 0; o < 3; ++o)
            for (int i = (A > 2 ? A - 2 : 0); i <= (A < 2 ? A : 2); ++i)
                for (int j = (Bq > 2 ? Bq - 2 : 0); j <= (Bq < 2 ? Bq : 2); ++j)
                    s += ksh[o * 9 + (A - i) * 3 + (Bq - j)] * ksh[o * 9 + (2 - i) * 3 + (2 - j)];
        K2sh[tid] = s;
    } else if (tid < 35) {
        const int Bq = (tid - 25) % 5;
        const int krow = (tid < 30) ? 6 : 0;
        float s = 0.f;
        for (int o = 0; o < 3; ++o)
            for (int j = (Bq > 2 ? Bq - 2 : 0); j <= (Bq < 2 ? Bq : 2); ++j)
                s += ksh[o * 9 + krow + (Bq - j)] * ksh[o * 9 + krow + (2 - j)];
        if (tid < 30) Ctop[Bq] = s; else Cbot[Bq] = s;
    } else if (tid < 65) {
        const int u = tid - 35;
        const int side = u / 15;
        const int v = (u % 15) / 5;
        const int A = u % 5;
        const int kcol = side ? 0 : 2;
        int ilo = (A > 2 ? A - 2 : 0), ihi = (A < 2 ? A : 2);
        if (v == 1 && ilo < 1) ilo = 1;
        if (v == 2 && ihi > 1) ihi = 1;
        float s = 0.f;
        for (int o = 0; o < 3; ++o)
            for (int i = ilo; i <= ihi; ++i)
                s += ksh[o * 9 + (A - i) * 3 + kcol] * ksh[o * 9 + (2 - i) * 3 + kcol];
        float* dst = side ? (v == 0 ? CRf : v == 1 ? CRt : CRb)
                          : (v == 0 ? CLf : v == 1 ? CLt : CLb);
        dst[A] = s;
    }
    __syncthreads();

#define STAGE_BORDER(SRC)                                                          \
    _Pragma("unroll")                                                              \
    for (int c = 0; c < 3; ++c) {                                                  \
        if (row < 2) {                                                             \
            _Pragma("unroll")                                                      \
            for (int cc = 0; cc < 4; ++cc)                                         \
                sstage[c * 256 + row * 32 + wb + cc] = SRC[c][cc];                 \
        }                                                                          \
        if (row >= 30) {                                                           \
            _Pragma("unroll")                                                      \
            for (int cc = 0; cc < 4; ++cc)                                         \
                sstage[c * 256 + 64 + (row - 30) * 32 + wb + cc] = SRC[c][cc];     \
        }                                                                          \
        if (wb == 0)  { sstage[c * 256 + 128 + row * 2]     = SRC[c][0];           \
                        sstage[c * 256 + 128 + row * 2 + 1] = SRC[c][1]; }         \
        if (wb == 28) { sstage[c * 256 + 192 + row * 2]     = SRC[c][2];           \
                        sstage[c * 256 + 192 + row * 2 + 1] = SRC[c][3]; }         \
    }

    // I-a: q0conv = PT(P(y)); b = m*q0conv + rho*(z-bet); x = b; publish b -> buf0
    {
        const float4 qv = conv_k2(dext, row, wb, h0, w0, K2sh, Ctop, Cbot,
                                  CLf, CLt, CLb, CRf, CRt, CRb);
        const float qa[4] = {qv.x, qv.y, qv.z, qv.w};
        #pragma unroll
        for (int c = 0; c < 3; ++c) {
            const int gi = (bi * 3 + c) * HW + roffb;
            const float4 zv = *(const float4*)(z + gi);
            const float4 bv = *(const float4*)(bet + gi);
            const float zz[4] = {zv.x, zv.y, zv.z, zv.w};
            const float bb[4] = {bv.x, bv.y, bv.z, bv.w};
            #pragma unroll
            for (int cc = 0; cc < 4; ++cc)
                x_[c][cc] = m_[c][cc] * qa[cc] + rho * (zz[cc] - bb[cc]);
        }
    }
    STAGE_BORDER(x_)
    __syncthreads();
    for (int t = tid; t < STRIP_F; t += TPB)
        ST_AG(strip + T * STRIP_F + t, sstage[t]);

    // finish population count -> xn, ng (opaque RMW polls)
    if (tid == 0) {
        while (__hip_atomic_fetch_add(cu + 144, opq0u(), __ATOMIC_RELAXED,
                                      __HIP_MEMORY_SCOPE_AGENT) < (unsigned)NBLK)
            __builtin_amdgcn_s_sleep(32);
        ng = 0;
        #pragma unroll
        for (int i = 0; i < 8; ++i) {
            unsigned c = __hip_atomic_fetch_add(cu + 160 + 16 * i, opq0u(),
                             __ATOMIC_RELAXED, __HIP_MEMORY_SCOPE_AGENT);
            ng += (c > 0u);
        }
        xn = __hip_atomic_fetch_add(cu + 160 + 16 * my_xcc, opq0u(),
                 __ATOMIC_RELAXED, __HIP_MEMORY_SCOPE_AGENT);
    }
    unsigned rnd = 1;
    frb2(0.f, 0.f, rnd++, ctrl, my_xcc, xn, ng);     // b strips visible

    // ---- I-b: d0 = sum m*b; r0 = b - A(b); gamma0; publish r0 -> buf1
    {
        float* dp = dext + (row + 2) * 36 + 2 + wb;
        #pragma unroll
        for (int cc = 0; cc < 4; ++cc)
            dp[cc] = m_[0][cc] * x_[0][cc] + m_[1][cc] * x_[1][cc] + m_[2][cc] * x_[2][cc];
    }
    for (int t = tid; t < 272; t += TPB) {
        int eh, ew; ring_pos(t, eh, ew);
        const int src = ringsrc[t];
        float s = 0.f;
        if (src >= 0) {
            #pragma unroll
            for (int c = 0; c < 3; ++c)
                s += m_ring[c][t] * LD_AG(strip + src + c * 256);
        }
        dext[eh * 36 + ew] = s;
    }
    __syncthreads();
    float gsum0 = 0.f;
    {
        const float4 qv = conv_k2(dext, row, wb, h0, w0, K2sh, Ctop, Cbot,
                                  CLf, CLt, CLb, CRf, CRt, CRb);
        const float qa[4] = {qv.x, qv.y, qv.z, qv.w};
        #pragma unroll
        for (int c = 0; c < 3; ++c)
            #pragma unroll
            for (int cc = 0; cc < 4; ++cc) {
                const float b = x_[c][cc];
                const float rv = b - (rho * b + m_[c][cc] * qa[cc]);
                r_[c][cc] = rv; p_[c][cc] = rv;
                gsum0 += rv * rv;
            }
    }
    STAGE_BORDER(r_)
    __syncthreads();
    for (int t = tid; t < STRIP_F; t += TPB)
        ST_AG(strip + STRIPBUF + T * STRIP_F + t, sstage[t]);

    float gamma = frb2(gsum0, 0.f, rnd++, ctrl, my_xcc, xn, ng).x;  // r0 visible

    // r_ring <- r0 halo
    for (int t = tid; t < 272; t += TPB) {
        const int src = ringsrc[t];
        if (src >= 0) {
            #pragma unroll
            for (int c = 0; c < 3; ++c)
                r_ring[c][t] = LD_AG(strip + STRIPBUF + src + c * 256);
        }
    }

    // ---- I-c: w0 = A(r0); delta0 = r0.w0; q = w0; publish w0 -> buf0
    {
        float* dp = dext + (row + 2) * 36 + 2 + wb;
        #pragma unroll
        for (int cc = 0; cc < 4; ++cc)
            dp[cc] = m_[0][cc] * r_[0][cc] + m_[1][cc] * r_[1][cc] + m_[2][cc] * r_[2][cc];
    }
    for (int t = tid; t < 272; t += TPB) {
        int eh, ew; ring_pos(t, eh, ew);
        float s = 0.f;
        #pragma unroll
        for (int c = 0; c < 3; ++c) s += m_ring[c][t] * r_ring[c][t];
        dext[eh * 36 + ew] = s;
    }
    __syncthreads();
    float dsum0 = 0.f;
    {
        const float4 qv = conv_k2(dext, row, wb, h0, w0, K2sh, Ctop, Cbot,
                                  CLf, CLt, CLb, CRf, CRt, CRb);
        const float qa[4] = {qv.x, qv.y, qv.z, qv.w};
        #pragma unroll
        for (int c = 0; c < 3; ++c)
            #pragma unroll
            for (int cc = 0; cc < 4; ++cc) {
                const float wv = rho * r_[c][cc] + m_[c][cc] * qa[cc];
                q_[c][cc] = wv;
                dsum0 += r_[c][cc] * wv;
            }
    }
    STAGE_BORDER(q_)
    __syncthreads();
    for (int t = tid; t < STRIP_F; t += TPB)
        ST_AG(strip + T * STRIP_F + t, sstage[t]);

    const float delta0 = frb2(dsum0, 0.f, rnd++, ctrl, my_xcc, xn, ng).x; // w0 vis

    // q_ring <- w0 halo
    for (int t = tid; t < 272; t += TPB) {
        const int src = ringsrc[t];
        if (src >= 0) {
            #pragma unroll
            for (int c = 0; c < 3; ++c)
                q_ring[c][t] = LD_AG(strip + src + c * 256);
        }
    }
    float alpha = (gamma >= TOL) ? (gamma / delta0) : 0.f;

    // ---- CG loop: ONE frb2 per iteration (Chronopoulos-Gear CG).
    // beta = gamma'/gamma (both MEASURED -> no recurrence feedback, the R8
    // failure mode); alpha' = gamma'/(delta' - beta*gamma'/alpha).
    for (int j = 0; j < NITER; ++j) {
        const bool active = (gamma >= TOL);

        if (active) {
            #pragma unroll
            for (int c = 0; c < 3; ++c)
                #pragma unroll
                for (int cc = 0; cc < 4; ++cc) {
                    x_[c][cc] += alpha * p_[c][cc];
                    r_[c][cc] -= alpha * q_[c][cc];
                }
            for (int t = tid; t < 272; t += TPB) {
                #pragma unroll
                for (int c = 0; c < 3; ++c)
                    r_ring[c][t] -= alpha * q_ring[c][t];
            }
        }

        // w = A(r): d = sum m*r (core + ring)
        {
            float* dp = dext + (row + 2) * 36 + 2 + wb;
            #pragma unroll
            for (int cc = 0; cc < 4; ++cc)
                dp[cc] = m_[0][cc] * r_[0][cc] + m_[1][cc] * r_[1][cc] + m_[2][cc] * r_[2][cc];
        }
        for (int t = tid; t < 272; t += TPB) {
            int eh, ew; ring_pos(t, eh, ew);
            float s = 0.f;
            #pragma unroll
            for (int c = 0; c < 3; ++c) s += m_ring[c][t] * r_ring[c][t];
            dext[eh * 36 + ew] = s;
        }
        __syncthreads();
        float gsum = 0.f, dsum = 0.f;
        {
            const float4 qv = conv_k2(dext, row, wb, h0, w0, K2sh, Ctop, Cbot,
                                      CLf, CLt, CLb, CRf, CRt, CRb);
            const float qa[4] = {qv.x, qv.y, qv.z, qv.w};
            #pragma unroll
            for (int c = 0; c < 3; ++c)
                #pragma unroll
                for (int cc = 0; cc < 4; ++cc) {
                    const float rv = r_[c][cc];
                    const float wv = rho * rv + m_[c][cc] * qa[cc];
                    w_[c][cc] = wv;
                    gsum += rv * rv;
                    dsum += rv * wv;
                }
        }
        // publish w strips (pre-frb; frb is the separating barrier).
        STAGE_BORDER(w_)
        __syncthreads();
        float* gb = strip + ((j + 1) & 1) * STRIPBUF;
        for (int t = tid; t < STRIP_F; t += TPB)
            ST_AG(gb + T * STRIP_F + t, sstage[t]);

        const float2 gd = frb2(gsum, dsum, rnd++, ctrl, my_xcc, xn, ng);

        if (active) {
            const float gp = gd.x, dp = gd.y;
            const float beta = gp / gamma;
            const float alphan = gp / (dp - beta * gp / alpha);
            #pragma unroll
            for (int c = 0; c < 3; ++c)
                #pragma unroll
                for (int cc = 0; cc < 4; ++cc) {
                    p_[c][cc] = r_[c][cc] + beta * p_[c][cc];
                    q_[c][cc] = w_[c][cc] + beta * q_[c][cc];
                }
            for (int t = tid; t < 272; t += TPB) {
                const int src = ringsrc[t];
                if (src >= 0) {
                    #pragma unroll
                    for (int c = 0; c < 3; ++c) {
                        const float wn = LD_AG(gb + src + c * 256);
                        q_ring[c][t] = wn + beta * q_ring[c][t];
                    }
                }
            }
            gamma = gp;
            alpha = alphan;
        }
    }

    #pragma unroll
    for (int c = 0; c < 3; ++c)
        *(float4*)(x_out + (bi * 3 + c) * HW + roffb) =
            make_float4(x_[c][0], x_[c][1], x_[c][2], x_[c][3]);
}

extern "C" void kernel_launch(void* const* d_in, const int* in_sizes, int n_in,
                              void* d_out, int out_size, void* d_ws, size_t ws_size,
                              hipStream_t stream)
{
    const float* mask = (const float*)d_in[0];
    const float* y    = (const float*)d_in[1];
    const float* z    = (const float*)d_in[2];
    const float* bet  = (const float*)d_in[3];
    const float* rho  = (const float*)d_in[4];
    const float* kern = (const float*)d_in[5];
    float* x  = (float*)d_out;
    float* ws = (float*)d_ws;

    hipMemsetAsync(ws + WS_CTRL, 0, CTRL_F * sizeof(float), stream);

    void* args[] = { (void*)&mask, (void*)&y, (void*)&z, (void*)&bet,
                     (void*)&rho, (void*)&kern, (void*)&x, (void*)&ws };
    hipLaunchCooperativeKernel((void*)cg_persistent, dim3(NBLK), dim3(TPB),
                               args, 0, stream);
}